// Round 7
// baseline (570.493 us; speedup 1.0000x reference)
//
#include <hip/hip_runtime.h>
#include <math.h>

#define FEAT 256
#define RANKK 16
#define PRJ_NODES 16
#define CAND_CAP 131072
#define TIE_CAP 2048
#define NBK_MAX 512   // max buckets (nhe/256)
#define PB_CHUNK 8192

typedef unsigned long long u64;

static __device__ __forceinline__ u64 pack_pair(unsigned e_low, unsigned bits, unsigned idx) {
    // [63:56]=e&255, [55:26]=score bits (<2^30 since score<=1.0f), [25:0]=idx
    return ((u64)e_low << 56) | ((u64)bits << 26) | (u64)idx;
}

// ========== K1: bucket histogram of E_idx>>8 + last-block exclusive scan ==========
__global__ __launch_bounds__(256) void ehist_scan(const int* __restrict__ E_idx,
        unsigned* __restrict__ bucketCnt, unsigned* __restrict__ bucketBase,
        unsigned* __restrict__ cursor, unsigned* __restrict__ ticket, int nnz) {
    __shared__ unsigned h[NBK_MAX];
    __shared__ unsigned ps[256];
    __shared__ unsigned isLast;
    int t = threadIdx.x;
    for (int j = t; j < NBK_MAX; j += 256) h[j] = 0;
    __syncthreads();
    for (int i = blockIdx.x * 256 + t; i < nnz; i += gridDim.x * 256)
        atomicAdd(&h[((unsigned)E_idx[i]) >> 8], 1u);
    __syncthreads();
    for (int j = t; j < NBK_MAX; j += 256)
        if (h[j]) atomicAdd(&bucketCnt[j], h[j]);
    __threadfence();
    if (t == 0) isLast = (atomicAdd(ticket, 1u) == gridDim.x - 1) ? 1u : 0u;
    __syncthreads();
    if (!isLast) return;
    // exclusive scan of 512 bins with 256 threads (atomic-reads for coherence)
    unsigned a0 = atomicAdd(&bucketCnt[2 * t], 0u);
    unsigned a1 = atomicAdd(&bucketCnt[2 * t + 1], 0u);
    unsigned pairsum = a0 + a1;
    ps[t] = pairsum;
    __syncthreads();
    for (int off = 1; off < 256; off <<= 1) {
        unsigned v = (t >= off) ? ps[t - off] : 0u;
        __syncthreads();
        ps[t] += v;
        __syncthreads();
    }
    unsigned excl = ps[t] - pairsum;
    bucketBase[2 * t] = excl;           cursor[2 * t] = excl;
    bucketBase[2 * t + 1] = excl + a0;  cursor[2 * t + 1] = excl + a0;
    if (t == 255) bucketBase[NBK_MAX] = ps[255];   // == nnz
}

// ========== K2: gather_ef + proj combo ==========
__global__ __launch_bounds__(256) void prep_combo(
        const float4* __restrict__ ef, const int* __restrict__ edge_ids,
        float4* __restrict__ ef2, int nhe,
        const float* __restrict__ x, const float* __restrict__ Wm,
        float* __restrict__ proj, int n_nodes, int G) {
    __shared__ float Ws[RANKK][FEAT + 4];
    __shared__ float Xs[PRJ_NODES][FEAT + 4];
    if ((int)blockIdx.x < G) {
        int t = blockIdx.x * 256 + threadIdx.x;
        if (t < nhe * 4) {
            int e = t >> 2, c = t & 3;
            ef2[(size_t)e * 4 + c] = ef[(size_t)edge_ids[e] * 4 + c];
        }
        return;
    }
    int pb = blockIdx.x - G;
    const float4* x4 = (const float4*)x;
    const float4* w4 = (const float4*)Wm;
    for (int t = threadIdx.x; t < RANKK * (FEAT / 4); t += 256) {
        int r = t >> 6, j4 = t & 63;
        *(float4*)&Ws[r][j4 * 4] = w4[t];
    }
    int nodeBase = pb * PRJ_NODES;
    for (int t = threadIdx.x; t < PRJ_NODES * (FEAT / 4); t += 256) {
        int n = t >> 6, j4 = t & 63;
        int node = nodeBase + n;
        float4 v = make_float4(0.f, 0.f, 0.f, 0.f);
        if (node < n_nodes) v = x4[(size_t)node * (FEAT / 4) + j4];
        *(float4*)&Xs[n][j4 * 4] = v;
    }
    __syncthreads();
    int n = threadIdx.x >> 4, r = threadIdx.x & 15;
    int node = nodeBase + n;
    if (node >= n_nodes) return;
    double acc = 0.0;
    #pragma unroll 8
    for (int j4 = 0; j4 < FEAT / 4; ++j4) {
        float4 xv = *(const float4*)&Xs[n][j4 * 4];
        float4 wv = *(const float4*)&Ws[r][j4 * 4];
        acc += (double)xv.x * (double)wv.x + (double)xv.y * (double)wv.y
             + (double)xv.z * (double)wv.z + (double)xv.w * (double)wv.w;
    }
    proj[(size_t)node * RANKK + r] = (float)acc;
}

// ========== K3: pure score kernel (round-4 form: gather, f64 dot, sigmoid, store) ==========
__global__ __launch_bounds__(256) void score_kernel(
        const float4* __restrict__ proj4, const float4* __restrict__ ef4,
        const int* __restrict__ V_idx, const int* __restrict__ E_idx,
        float* __restrict__ scores, int nnz) {
    int stride = gridDim.x * blockDim.x;
    #pragma unroll 2
    for (int i = blockIdx.x * blockDim.x + threadIdx.x; i < nnz; i += stride) {
        int v = V_idx[i], e = E_idx[i];
        float4 p0 = proj4[(size_t)v * 4 + 0];
        float4 p1 = proj4[(size_t)v * 4 + 1];
        float4 p2 = proj4[(size_t)v * 4 + 2];
        float4 p3 = proj4[(size_t)v * 4 + 3];
        float4 f0 = ef4[(size_t)e * 4 + 0];
        float4 f1 = ef4[(size_t)e * 4 + 1];
        float4 f2 = ef4[(size_t)e * 4 + 2];
        float4 f3 = ef4[(size_t)e * 4 + 3];
        double acc = (double)p0.x * f0.x + (double)p0.y * f0.y + (double)p0.z * f0.z + (double)p0.w * f0.w
                   + (double)p1.x * f1.x + (double)p1.y * f1.y + (double)p1.z * f1.z + (double)p1.w * f1.w
                   + (double)p2.x * f2.x + (double)p2.y * f2.y + (double)p2.z * f2.z + (double)p2.w * f2.w
                   + (double)p3.x * f3.x + (double)p3.y * f3.y + (double)p3.z * f3.z + (double)p3.w * f3.w;
        scores[i] = (float)(1.0 / (1.0 + exp(-acc)));
    }
}

// ========== K4: pair_build + level-1 histogram + last-block scan1 ==========
__global__ __launch_bounds__(256) void pair_hist_scan(const int* __restrict__ E_idx,
        const float* __restrict__ scores, u64* __restrict__ pairs,
        unsigned* __restrict__ cursor, unsigned* __restrict__ hist1g,
        unsigned* __restrict__ ticket, unsigned* __restrict__ sel,
        const int* __restrict__ kptr, int nnz, int nb) {
    __shared__ unsigned bh[NBK_MAX];
    __shared__ unsigned h[4096];
    __shared__ unsigned sfx[256];
    __shared__ unsigned isLast;
    int t = threadIdx.x;
    for (int j = t; j < NBK_MAX; j += 256) bh[j] = 0;
    for (int j = t; j < 4096; j += 256) h[j] = 0;
    __syncthreads();
    int base = blockIdx.x * PB_CHUNK;
    int nE = nnz - base;
    if (nE > PB_CHUNK) nE = PB_CHUNK;
    // pass 1: per-block bucket counts + score histogram (hot bins in regs)
    unsigned r1016 = 0, r1015 = 0, r0 = 0;
    for (int o = t; o < nE; o += 256) {
        atomicAdd(&bh[((unsigned)E_idx[base + o]) >> 8], 1u);
        unsigned b = __float_as_uint(scores[base + o]) >> 20;
        if (b == 1016) ++r1016;
        else if (b == 1015) ++r1015;
        else if (b == 0) ++r0;
        else atomicAdd(&h[b], 1u);
    }
    if (r1016) atomicAdd(&h[1016], r1016);
    if (r1015) atomicAdd(&h[1015], r1015);
    if (r0) atomicAdd(&h[0], r0);
    __syncthreads();
    // allocate bucket ranges
    for (int b = t; b < nb; b += 256) {
        unsigned c = bh[b];
        bh[b] = c ? atomicAdd(&cursor[b], c) : 0u;
    }
    // flush score histogram
    for (int j = t; j < 4096; j += 256)
        if (h[j]) atomicAdd(&hist1g[j], h[j]);
    __syncthreads();
    // pass 2: scatter pairs in bucket order
    for (int o = t; o < nE; o += 256) {
        int i = base + o;
        unsigned e = (unsigned)E_idx[i];
        unsigned bits = __float_as_uint(scores[i]);
        unsigned pos = atomicAdd(&bh[e >> 8], 1u);
        pairs[pos] = pack_pair(e & 255u, bits, (unsigned)i);
    }
    __threadfence();
    if (t == 0) isLast = (atomicAdd(ticket, 1u) == gridDim.x - 1) ? 1u : 0u;
    __syncthreads();
    if (!isLast) return;
    // ---- scan1: suffix scan of 4096-bin histogram, find cutoff bin ----
    unsigned local[16];
    unsigned s = 0;
    #pragma unroll
    for (int j = 0; j < 16; ++j) { local[j] = atomicAdd(&hist1g[t * 16 + j], 0u); s += local[j]; }
    sfx[t] = s;
    __syncthreads();
    for (int off = 1; off < 256; off <<= 1) {
        unsigned add = (t + off < 256) ? sfx[t + off] : 0;
        __syncthreads();
        sfx[t] += add;
        __syncthreads();
    }
    unsigned krem = (unsigned)(*kptr);
    unsigned above = (t + 1 < 256) ? sfx[t + 1] : 0;
    if (above < krem && sfx[t] >= krem) {
        unsigned cum = above;
        int b = t * 16;
        for (int j = 15; j >= 0; --j) {
            unsigned cc = local[j];
            if (cum + cc >= krem) { b = t * 16 + j; break; }
            cum += cc;
        }
        sel[0] = krem - cum;            // remaining k within bin b
        sel[1] = ((unsigned)b) << 20;   // 12-bit prefix
    }
}

// ========== K5: compact candidates (from scores) ==========
__global__ void compact_kernel(const float4* __restrict__ scores4,
                               const unsigned* __restrict__ sel,
                               uint2* __restrict__ cand, unsigned* __restrict__ candCount,
                               int n4, int nnz) {
    unsigned pref = sel[1] >> 20;
    int tid = blockIdx.x * blockDim.x + threadIdx.x;
    int stride = gridDim.x * blockDim.x;
    int lane = threadIdx.x & 63;
    int niter = (n4 + stride - 1) / stride;
    for (int kk = 0; kk < niter; ++kk) {
        int i = tid + kk * stride;
        bool inb = (i < n4);
        float4 sv = make_float4(0.f, 0.f, 0.f, 0.f);
        if (inb) sv = scores4[i];
        unsigned bb[4] = {__float_as_uint(sv.x), __float_as_uint(sv.y),
                          __float_as_uint(sv.z), __float_as_uint(sv.w)};
        #pragma unroll
        for (int q = 0; q < 4; ++q) {
            bool pred = inb && ((bb[q] >> 20) == pref);
            unsigned long long mask = __ballot(pred);
            if (mask) {
                int leader = __ffsll(mask) - 1;
                unsigned base = 0;
                if (lane == leader) base = atomicAdd(candCount, (unsigned)__popcll(mask));
                base = __shfl(base, leader, 64);
                if (pred) {
                    unsigned rank = __popcll(mask & ((1ull << lane) - 1ull));
                    unsigned pos = base + rank;
                    if (pos < CAND_CAP) cand[pos] = make_uint2(bb[q], (unsigned)(i * 4 + q));
                }
            }
        }
    }
    for (int i = n4 * 4 + tid; i < nnz; i += stride) {
        unsigned b = __float_as_uint(((const float*)scores4)[i]);
        if ((b >> 20) == pref) {
            unsigned pos = atomicAdd(candCount, 1u);
            if (pos < CAND_CAP) cand[pos] = make_uint2(b, (unsigned)i);
        }
    }
}

// ========== K6: single-block selection among candidates ==========
__global__ __launch_bounds__(256) void select_small(const uint2* __restrict__ cand,
                            const unsigned* __restrict__ candCount,
                            unsigned* __restrict__ sel, unsigned* __restrict__ tieList) {
    __shared__ unsigned h2[4096];
    __shared__ unsigned sfx[256];
    __shared__ unsigned sB2, sKrem2, sT, sM;
    __shared__ unsigned h3[256];
    __shared__ unsigned ties[TIE_CAP];
    __shared__ unsigned tcnt;
    int t = threadIdx.x;
    unsigned nc = *candCount;
    int n = (nc < CAND_CAP) ? (int)nc : CAND_CAP;
    unsigned krem = sel[0];
    unsigned pref = sel[1];

    for (int j = t; j < 4096; j += 256) h2[j] = 0;
    if (t == 0) tcnt = 0;
    __syncthreads();
    for (int j = t; j < n; j += 256) atomicAdd(&h2[(cand[j].x >> 8) & 0xFFF], 1u);
    __syncthreads();

    unsigned local[16];
    unsigned s = 0;
    #pragma unroll
    for (int j = 0; j < 16; ++j) { local[j] = h2[t * 16 + j]; s += local[j]; }
    sfx[t] = s;
    __syncthreads();
    for (int off = 1; off < 256; off <<= 1) {
        unsigned add = (t + off < 256) ? sfx[t + off] : 0;
        __syncthreads();
        sfx[t] += add;
        __syncthreads();
    }
    {
        unsigned above = (t + 1 < 256) ? sfx[t + 1] : 0;
        if (above < krem && sfx[t] >= krem) {
            unsigned cum = above;
            int b = t * 16;
            for (int j = 15; j >= 0; --j) {
                unsigned cc = local[j];
                if (cum + cc >= krem) { b = t * 16 + j; break; }
                cum += cc;
            }
            sB2 = (unsigned)b;
            sKrem2 = krem - cum;
        }
    }
    __syncthreads();

    h3[t] = 0;
    __syncthreads();
    unsigned b2 = sB2;
    for (int j = t; j < n; j += 256) {
        unsigned x = cand[j].x;
        if (((x >> 8) & 0xFFF) == b2) atomicAdd(&h3[x & 0xFF], 1u);
    }
    __syncthreads();
    sfx[t] = h3[t];
    __syncthreads();
    for (int off = 1; off < 256; off <<= 1) {
        unsigned add = (t + off < 256) ? sfx[t + off] : 0;
        __syncthreads();
        sfx[t] += add;
        __syncthreads();
    }
    {
        unsigned krem2 = sKrem2;
        unsigned above = (t + 1 < 256) ? sfx[t + 1] : 0;
        if (above < krem2 && sfx[t] >= krem2) {
            sT = pref | (b2 << 8) | (unsigned)t;
            sM = krem2 - above;
        }
    }
    __syncthreads();

    unsigned T = sT;
    for (int j = t; j < n; j += 256) {
        if (cand[j].x == T) {
            unsigned p = atomicAdd(&tcnt, 1u);
            if (p < TIE_CAP) ties[p] = cand[j].y;
        }
    }
    __syncthreads();
    if (t == 0) {
        unsigned cnt = (tcnt < TIE_CAP) ? tcnt : TIE_CAP;
        for (unsigned a = 1; a < cnt; ++a) {
            unsigned key = ties[a];
            int bpos = (int)a - 1;
            while (bpos >= 0 && ties[bpos] > key) { ties[bpos + 1] = ties[bpos]; --bpos; }
            ties[bpos + 1] = key;
        }
        unsigned m = sM;
        if (m > cnt) m = cnt;
        sel[2] = T;
        sel[3] = m;
        for (unsigned j = 0; j < m; ++j) tieList[j] = ties[j];
    }
}

// ========== K7: per-bucket edge stats + finalize (reads pairs; runs BEFORE write_hard) ==========
__global__ __launch_bounds__(256) void edge_final(const u64* __restrict__ pairs,
        const unsigned* __restrict__ bucketBase, const unsigned* __restrict__ sel,
        const unsigned* __restrict__ tieList,
        float* __restrict__ eprob, float* __restrict__ esoft, float* __restrict__ ehard,
        int nhe) {
    __shared__ float ss[256];
    __shared__ unsigned cc[256];
    __shared__ unsigned hh[256];
    __shared__ unsigned ties[TIE_CAP];
    unsigned T = sel[2];
    unsigned m = sel[3];
    if (m > TIE_CAP) m = TIE_CAP;
    int t = threadIdx.x;
    ss[t] = 0.f; cc[t] = 0u; hh[t] = 0u;
    for (int j = t; j < (int)m; j += 256) ties[j] = tieList[j];
    __syncthreads();
    int b = blockIdx.x;
    unsigned n0 = bucketBase[b], n1 = bucketBase[b + 1];
    for (unsigned j = n0 + t; j < n1; j += 256) {
        u64 p = pairs[j];
        unsigned el = (unsigned)(p >> 56);
        unsigned bits = (unsigned)(p >> 26) & 0x3FFFFFFFu;
        atomicAdd(&ss[el], __uint_as_float(bits));
        atomicAdd(&cc[el], 1u);
        bool keep = bits > T;
        if (bits == T) {
            unsigned idx = (unsigned)(p & 0x3FFFFFFu);
            int lo = 0, hi = (int)m - 1;
            keep = false;
            while (lo <= hi) {
                int mid = (lo + hi) >> 1;
                unsigned v = ties[mid];
                if (v == idx) { keep = true; break; }
                if (v < idx) lo = mid + 1; else hi = mid - 1;
            }
        }
        if (keep) atomicAdd(&hh[el], 1u);
    }
    __syncthreads();
    int e = b * 256 + t;
    if (e < nhe) {
        float c = fmaxf((float)cc[t], 1.0f);
        eprob[e] = ss[t] / c;
        esoft[e] = (float)hh[t] / c;
        ehard[e] = (hh[t] > 0) ? 1.0f : 0.0f;
    }
}

// ========== K8: hard/soft classification (overwrites the pairs region; runs AFTER K7) ==========
__global__ __launch_bounds__(256) void write_hard(const float4* __restrict__ scores4,
                           const unsigned* __restrict__ sel,
                           const unsigned* __restrict__ tieList,
                           float4* __restrict__ hard4, float4* __restrict__ soft4,
                           int n4, int nnz) {
    __shared__ unsigned ties[TIE_CAP];
    unsigned T = sel[2];
    unsigned m = sel[3];
    if (m > TIE_CAP) m = TIE_CAP;
    for (int j = threadIdx.x; j < (int)m; j += blockDim.x) ties[j] = tieList[j];
    __syncthreads();
    int tid = blockIdx.x * blockDim.x + threadIdx.x;
    int stride = gridDim.x * blockDim.x;
    for (int i = tid; i < n4; i += stride) {
        float4 sv = scores4[i];
        unsigned bb[4] = {__float_as_uint(sv.x), __float_as_uint(sv.y),
                          __float_as_uint(sv.z), __float_as_uint(sv.w)};
        float hv[4];
        #pragma unroll
        for (int q = 0; q < 4; ++q) {
            bool keep = (bb[q] > T);
            if (bb[q] == T) {
                unsigned idx = (unsigned)(i * 4 + q);
                int lo = 0, hi = (int)m - 1;
                keep = false;
                while (lo <= hi) {
                    int mid = (lo + hi) >> 1;
                    unsigned v = ties[mid];
                    if (v == idx) { keep = true; break; }
                    if (v < idx) lo = mid + 1; else hi = mid - 1;
                }
            }
            hv[q] = keep ? 1.0f : 0.0f;
        }
        float4 outv = make_float4(hv[0], hv[1], hv[2], hv[3]);
        hard4[i] = outv;
        soft4[i] = outv;
    }
    const float* sc = (const float*)scores4;
    float* hard = (float*)hard4;
    float* soft = (float*)soft4;
    for (int i = n4 * 4 + tid; i < nnz; i += stride) {
        unsigned b = __float_as_uint(sc[i]);
        bool keep = (b > T);
        if (b == T) {
            unsigned idx = (unsigned)i;
            int lo = 0, hi = (int)m - 1;
            keep = false;
            while (lo <= hi) {
                int mid = (lo + hi) >> 1;
                unsigned v = ties[mid];
                if (v == idx) { keep = true; break; }
                if (v < idx) lo = mid + 1; else hi = mid - 1;
            }
        }
        float hvv = keep ? 1.0f : 0.0f;
        hard[i] = hvv;
        soft[i] = hvv;
    }
}

extern "C" void kernel_launch(void* const* d_in, const int* in_sizes, int n_in,
                              void* d_out, int out_size, void* d_ws, size_t ws_size,
                              hipStream_t stream) {
    const float* x        = (const float*)d_in[0];
    const float* Wm       = (const float*)d_in[1];
    const float* ef       = (const float*)d_in[2];
    const int*   V_idx    = (const int*)d_in[3];
    const int*   E_idx    = (const int*)d_in[4];
    const int*   edge_ids = (const int*)d_in[5];
    const int*   kptr     = (const int*)d_in[6];

    const int nnz     = in_sizes[3];
    const int nhe     = in_sizes[5];
    const int n_nodes = in_sizes[0] / FEAT;
    const int nb      = (nhe + 255) >> 8;   // buckets of 256 edges (<= NBK_MAX)

    float* out    = (float*)d_out;
    float* scores = out;
    float* soft   = out + (size_t)nnz;
    float* hard   = out + 2 * (size_t)nnz;
    float* eprob  = out + 3 * (size_t)nnz;
    float* esoft  = eprob + nhe;
    float* ehard  = esoft + nhe;

    // pairs live in soft+hard (exactly nnz u64); consumed by edge_final BEFORE
    // write_hard overwrites the region (sequential dispatches — do not fuse).
    u64*   pairs = (u64*)soft;
    // cand lives in eprob+esoft+ehard (1 MB <= 1.43 MB); consumed by select_small
    // before edge_final writes eprob.
    uint2* cand  = (uint2*)eprob;

    // ---- aux zone in d_ws ----
    char* w = (char*)d_ws;
    unsigned* hist1      = (unsigned*)w;               // 4096
    unsigned* bucketCnt  = hist1 + 4096;               // NBK_MAX
    unsigned* candCount  = bucketCnt + NBK_MAX;        // 1
    unsigned* ticket1    = candCount + 1;              // 1
    unsigned* ticket2    = ticket1 + 1;                // 1
    unsigned* sel        = ticket2 + 1;                // 8
    unsigned* tieList    = sel + 8;                    // TIE_CAP
    unsigned* bucketBase = tieList + TIE_CAP;          // NBK_MAX+1
    unsigned* cursor     = bucketBase + NBK_MAX + 1;   // NBK_MAX
    char* auxEnd = (char*)(cursor + NBK_MAX);
    size_t auxAligned = (((size_t)(auxEnd - w)) + 255) & ~(size_t)255;
    size_t zeroBytes = (size_t)(4096 + NBK_MAX + 3) * sizeof(unsigned);

    size_t ef2Bytes  = (size_t)nhe * RANKK * sizeof(float);
    size_t projBytes = (size_t)n_nodes * RANKK * sizeof(float);

    float* ef2;
    float* proj;
    if (ws_size >= auxAligned + ef2Bytes + projBytes) {
        ef2  = (float*)(w + auxAligned);
        proj = (float*)(w + auxAligned + ef2Bytes);
    } else {
        // hard region (nnz floats >= ef2+proj): consumed by score_kernel,
        // which finishes before pair/write kernels touch hard.
        ef2  = hard;
        proj = hard + (size_t)nhe * RANKK;
    }

    hipMemsetAsync(w, 0, zeroBytes, stream);

    ehist_scan<<<128, 256, 0, stream>>>(E_idx, bucketCnt, bucketBase, cursor, ticket1, nnz);

    int G = (nhe * 4 + 255) / 256;
    int P = (n_nodes + PRJ_NODES - 1) / PRJ_NODES;
    prep_combo<<<G + P, 256, 0, stream>>>((const float4*)ef, edge_ids, (float4*)ef2, nhe,
                                          x, Wm, proj, n_nodes, G);

    score_kernel<<<2048, 256, 0, stream>>>(
        (const float4*)proj, (const float4*)ef2, V_idx, E_idx, scores, nnz);

    pair_hist_scan<<<(nnz + PB_CHUNK - 1) / PB_CHUNK, 256, 0, stream>>>(
        E_idx, scores, pairs, cursor, hist1, ticket2, sel, kptr, nnz, nb);

    int n4 = nnz / 4;
    compact_kernel<<<1024, 256, 0, stream>>>(
        (const float4*)scores, sel, cand, candCount, n4, nnz);
    select_small<<<1, 256, 0, stream>>>(cand, candCount, sel, tieList);

    edge_final<<<nb, 256, 0, stream>>>(pairs, bucketBase, sel, tieList,
                                       eprob, esoft, ehard, nhe);
    write_hard<<<1024, 256, 0, stream>>>(
        (const float4*)scores, sel, tieList, (float4*)hard, (float4*)soft, n4, nnz);
}

// Round 8
// 474.998 us; speedup vs baseline: 1.2010x; 1.2010x over previous
//
#include <hip/hip_runtime.h>
#include <math.h>

#define FEAT 256
#define RANKK 16
#define PRJ_NODES 16
#define CAND_CAP 131072
#define TIE_CAP 2048
#define NBK_MAX 512   // max buckets (nhe/256)
#define PB_CHUNK 8192
#define SPLIT 4       // blocks per bucket in bucket_score

typedef unsigned long long u64;

static __device__ __forceinline__ u64 pack_pair(unsigned e_low, unsigned bits, unsigned idx) {
    // [63:56]=e&255, [55:26]=score bits (<2^30 since score<=1.0f), [25:0]=idx
    return ((u64)e_low << 56) | ((u64)bits << 26) | (u64)idx;
}

// vlist entry: [63:40]=v (24b), [31:8]=idx (24b), [7:0]=e&255
static __device__ __forceinline__ u64 pack_v(unsigned v, unsigned idx, unsigned e_low) {
    return ((u64)v << 40) | ((u64)idx << 8) | (u64)e_low;
}

// ========== K1: bucket histogram of E_idx>>8 + last-block exclusive scan ==========
__global__ __launch_bounds__(256) void ehist_scan(const int* __restrict__ E_idx,
        unsigned* __restrict__ bucketCnt, unsigned* __restrict__ bucketBase,
        unsigned* __restrict__ cursor, unsigned* __restrict__ ticket, int nnz) {
    __shared__ unsigned h[NBK_MAX];
    __shared__ unsigned ps[256];
    __shared__ unsigned isLast;
    int t = threadIdx.x;
    for (int j = t; j < NBK_MAX; j += 256) h[j] = 0;
    __syncthreads();
    for (int i = blockIdx.x * 256 + t; i < nnz; i += gridDim.x * 256)
        atomicAdd(&h[((unsigned)E_idx[i]) >> 8], 1u);
    __syncthreads();
    for (int j = t; j < NBK_MAX; j += 256)
        if (h[j]) atomicAdd(&bucketCnt[j], h[j]);
    __threadfence();
    if (t == 0) isLast = (atomicAdd(ticket, 1u) == gridDim.x - 1) ? 1u : 0u;
    __syncthreads();
    if (!isLast) return;
    unsigned a0 = atomicAdd(&bucketCnt[2 * t], 0u);
    unsigned a1 = atomicAdd(&bucketCnt[2 * t + 1], 0u);
    unsigned pairsum = a0 + a1;
    ps[t] = pairsum;
    __syncthreads();
    for (int off = 1; off < 256; off <<= 1) {
        unsigned v = (t >= off) ? ps[t - off] : 0u;
        __syncthreads();
        ps[t] += v;
        __syncthreads();
    }
    unsigned excl = ps[t] - pairsum;
    bucketBase[2 * t] = excl;           cursor[2 * t] = excl;
    bucketBase[2 * t + 1] = excl + a0;  cursor[2 * t + 1] = excl + a0;
    if (t == 255) bucketBase[NBK_MAX] = ps[255];   // == nnz
}

// ========== K2: gather_ef + proj combo ==========
__global__ __launch_bounds__(256) void prep_combo(
        const float4* __restrict__ ef, const int* __restrict__ edge_ids,
        float4* __restrict__ ef2, int nhe,
        const float* __restrict__ x, const float* __restrict__ Wm,
        float* __restrict__ proj, int n_nodes, int G) {
    __shared__ float Ws[RANKK][FEAT + 4];
    __shared__ float Xs[PRJ_NODES][FEAT + 4];
    if ((int)blockIdx.x < G) {
        int t = blockIdx.x * 256 + threadIdx.x;
        if (t < nhe * 4) {
            int e = t >> 2, c = t & 3;
            ef2[(size_t)e * 4 + c] = ef[(size_t)edge_ids[e] * 4 + c];
        }
        return;
    }
    int pb = blockIdx.x - G;
    const float4* x4 = (const float4*)x;
    const float4* w4 = (const float4*)Wm;
    for (int t = threadIdx.x; t < RANKK * (FEAT / 4); t += 256) {
        int r = t >> 6, j4 = t & 63;
        *(float4*)&Ws[r][j4 * 4] = w4[t];
    }
    int nodeBase = pb * PRJ_NODES;
    for (int t = threadIdx.x; t < PRJ_NODES * (FEAT / 4); t += 256) {
        int n = t >> 6, j4 = t & 63;
        int node = nodeBase + n;
        float4 v = make_float4(0.f, 0.f, 0.f, 0.f);
        if (node < n_nodes) v = x4[(size_t)node * (FEAT / 4) + j4];
        *(float4*)&Xs[n][j4 * 4] = v;
    }
    __syncthreads();
    int n = threadIdx.x >> 4, r = threadIdx.x & 15;
    int node = nodeBase + n;
    if (node >= n_nodes) return;
    double acc = 0.0;
    #pragma unroll 8
    for (int j4 = 0; j4 < FEAT / 4; ++j4) {
        float4 xv = *(const float4*)&Xs[n][j4 * 4];
        float4 wv = *(const float4*)&Ws[r][j4 * 4];
        acc += (double)xv.x * (double)wv.x + (double)xv.y * (double)wv.y
             + (double)xv.z * (double)wv.z + (double)xv.w * (double)wv.w;
    }
    proj[(size_t)node * RANKK + r] = (float)acc;
}

// ========== K3: sort incidences into bucket order (block-aggregated cursor alloc) ==========
__global__ __launch_bounds__(256) void sort_kernel(const int* __restrict__ V_idx,
        const int* __restrict__ E_idx, u64* __restrict__ vlist,
        unsigned* __restrict__ cursor, int nnz, int nb) {
    __shared__ unsigned bh[NBK_MAX];
    int t = threadIdx.x;
    for (int j = t; j < NBK_MAX; j += 256) bh[j] = 0;
    __syncthreads();
    int base = blockIdx.x * PB_CHUNK;
    int nE = nnz - base;
    if (nE > PB_CHUNK) nE = PB_CHUNK;
    for (int o = t; o < nE; o += 256)
        atomicAdd(&bh[((unsigned)E_idx[base + o]) >> 8], 1u);
    __syncthreads();
    for (int b = t; b < nb; b += 256) {
        unsigned c = bh[b];
        bh[b] = c ? atomicAdd(&cursor[b], c) : 0u;
    }
    __syncthreads();
    for (int o = t; o < nE; o += 256) {
        int i = base + o;
        unsigned e = (unsigned)E_idx[i];
        unsigned v = (unsigned)V_idx[i];
        unsigned pos = atomicAdd(&bh[e >> 8], 1u);
        vlist[pos] = pack_v(v, (unsigned)i, e & 255u);
    }
}

// ========== K4a (primary): bucket-ordered score; ef2 tile in LDS; pairs written in place ==========
__global__ __launch_bounds__(256) void bucket_score(
        const float4* __restrict__ proj4, const float4* __restrict__ ef4,
        const unsigned* __restrict__ bucketBase, u64* __restrict__ list,
        float* __restrict__ scores, int nhe) {
    __shared__ float efs[256][20];   // stride 20 floats: 16B-aligned rows, spread banks
    int t = threadIdx.x;
    int b = blockIdx.x >> 2;        // bucket
    int part = blockIdx.x & (SPLIT - 1);
    // stage ef2 rows of this bucket (256 edges x 4 float4, coalesced)
    for (int jj = t; jj < 1024; jj += 256) {
        int edge = (b << 8) + (jj >> 2);
        if (edge < nhe) {
            float4 v = ef4[(size_t)edge * 4 + (jj & 3)];
            *(float4*)&efs[jj >> 2][(jj & 3) * 4] = v;
        }
    }
    __syncthreads();
    unsigned n0 = bucketBase[b], n1 = bucketBase[b + 1];
    #pragma unroll 2
    for (unsigned j = n0 + (part << 8) + t; j < n1; j += SPLIT * 256) {
        u64 p = list[j];
        unsigned v   = (unsigned)(p >> 40);
        unsigned idx = (unsigned)(p >> 8) & 0xFFFFFFu;
        unsigned el  = (unsigned)(p & 255u);
        float4 p0 = proj4[(size_t)v * 4 + 0];
        float4 p1 = proj4[(size_t)v * 4 + 1];
        float4 p2 = proj4[(size_t)v * 4 + 2];
        float4 p3 = proj4[(size_t)v * 4 + 3];
        float4 f0 = *(const float4*)&efs[el][0];
        float4 f1 = *(const float4*)&efs[el][4];
        float4 f2 = *(const float4*)&efs[el][8];
        float4 f3 = *(const float4*)&efs[el][12];
        double acc = (double)p0.x * f0.x + (double)p0.y * f0.y + (double)p0.z * f0.z + (double)p0.w * f0.w
                   + (double)p1.x * f1.x + (double)p1.y * f1.y + (double)p1.z * f1.z + (double)p1.w * f1.w
                   + (double)p2.x * f2.x + (double)p2.y * f2.y + (double)p2.z * f2.z + (double)p2.w * f2.w
                   + (double)p3.x * f3.x + (double)p3.y * f3.y + (double)p3.z * f3.z + (double)p3.w * f3.w;
        float s = (float)(1.0 / (1.0 + exp(-acc)));
        scores[idx] = s;                                  // scatter (each idx once)
        list[j] = pack_pair(el, __float_as_uint(s), idx); // in-place vlist -> pairs
    }
}

// ========== K4b (fallback): linear score (r4/r7-proven) ==========
__global__ __launch_bounds__(256) void score_linear(
        const float4* __restrict__ proj4, const float4* __restrict__ ef4,
        const int* __restrict__ V_idx, const int* __restrict__ E_idx,
        float* __restrict__ scores, int nnz) {
    int stride = gridDim.x * blockDim.x;
    #pragma unroll 2
    for (int i = blockIdx.x * blockDim.x + threadIdx.x; i < nnz; i += stride) {
        int v = V_idx[i], e = E_idx[i];
        float4 p0 = proj4[(size_t)v * 4 + 0];
        float4 p1 = proj4[(size_t)v * 4 + 1];
        float4 p2 = proj4[(size_t)v * 4 + 2];
        float4 p3 = proj4[(size_t)v * 4 + 3];
        float4 f0 = ef4[(size_t)e * 4 + 0];
        float4 f1 = ef4[(size_t)e * 4 + 1];
        float4 f2 = ef4[(size_t)e * 4 + 2];
        float4 f3 = ef4[(size_t)e * 4 + 3];
        double acc = (double)p0.x * f0.x + (double)p0.y * f0.y + (double)p0.z * f0.z + (double)p0.w * f0.w
                   + (double)p1.x * f1.x + (double)p1.y * f1.y + (double)p1.z * f1.z + (double)p1.w * f1.w
                   + (double)p2.x * f2.x + (double)p2.y * f2.y + (double)p2.z * f2.z + (double)p2.w * f2.w
                   + (double)p3.x * f3.x + (double)p3.y * f3.y + (double)p3.z * f3.z + (double)p3.w * f3.w;
        scores[i] = (float)(1.0 / (1.0 + exp(-acc)));
    }
}

// ========== K4c (fallback): pair_build (r4-proven) ==========
__global__ __launch_bounds__(256) void pair_build(const int* __restrict__ E_idx,
        const float* __restrict__ scores, u64* __restrict__ pairs,
        unsigned* __restrict__ cursor, int nnz, int nb) {
    __shared__ unsigned bh[NBK_MAX];
    for (int t = threadIdx.x; t < NBK_MAX; t += 256) bh[t] = 0;
    __syncthreads();
    int base = blockIdx.x * PB_CHUNK;
    int nE = nnz - base;
    if (nE > PB_CHUNK) nE = PB_CHUNK;
    for (int o = threadIdx.x; o < nE; o += 256)
        atomicAdd(&bh[((unsigned)E_idx[base + o]) >> 8], 1u);
    __syncthreads();
    for (int b = threadIdx.x; b < nb; b += 256) {
        unsigned c = bh[b];
        bh[b] = c ? atomicAdd(&cursor[b], c) : 0u;
    }
    __syncthreads();
    for (int o = threadIdx.x; o < nE; o += 256) {
        int i = base + o;
        unsigned e = (unsigned)E_idx[i];
        unsigned bits = __float_as_uint(scores[i]);
        unsigned pos = atomicAdd(&bh[e >> 8], 1u);
        pairs[pos] = pack_pair(e & 255u, bits, (unsigned)i);
    }
}

// ========== K5: level-1 histogram over scores (r4-proven, hot bins in regs) ==========
__global__ void hist1_kernel(const float4* __restrict__ scores4, unsigned* __restrict__ hist1g,
                             int n4, int nnz) {
    __shared__ unsigned h[4096];
    for (int t = threadIdx.x; t < 4096; t += blockDim.x) h[t] = 0;
    __syncthreads();
    unsigned r1016 = 0, r1015 = 0, r0 = 0;
    int stride = gridDim.x * blockDim.x;
    for (int i = blockIdx.x * blockDim.x + threadIdx.x; i < n4; i += stride) {
        float4 sv = scores4[i];
        unsigned bb[4] = {__float_as_uint(sv.x), __float_as_uint(sv.y),
                          __float_as_uint(sv.z), __float_as_uint(sv.w)};
        #pragma unroll
        for (int q = 0; q < 4; ++q) {
            unsigned b = bb[q] >> 20;
            if (b == 1016) ++r1016;
            else if (b == 1015) ++r1015;
            else if (b == 0) ++r0;
            else atomicAdd(&h[b], 1u);
        }
    }
    for (int i = n4 * 4 + blockIdx.x * blockDim.x + threadIdx.x; i < nnz; i += stride) {
        unsigned b = __float_as_uint(((const float*)scores4)[i]) >> 20;
        if (b == 1016) ++r1016;
        else if (b == 1015) ++r1015;
        else if (b == 0) ++r0;
        else atomicAdd(&h[b], 1u);
    }
    if (r1016) atomicAdd(&h[1016], r1016);
    if (r1015) atomicAdd(&h[1015], r1015);
    if (r0) atomicAdd(&h[0], r0);
    __syncthreads();
    for (int t = threadIdx.x; t < 4096; t += blockDim.x)
        if (h[t]) atomicAdd(&hist1g[t], h[t]);
}

// ========== K6: parallel level-1 suffix scan (1 block, r4-proven) ==========
__global__ void scan1_kernel(const unsigned* __restrict__ hist,
                             unsigned* __restrict__ sel, const int* __restrict__ kptr) {
    __shared__ unsigned sfx[256];
    int t = threadIdx.x;
    unsigned local[16];
    unsigned s = 0;
    #pragma unroll
    for (int j = 0; j < 16; ++j) { local[j] = hist[t * 16 + j]; s += local[j]; }
    sfx[t] = s;
    __syncthreads();
    for (int off = 1; off < 256; off <<= 1) {
        unsigned add = (t + off < 256) ? sfx[t + off] : 0;
        __syncthreads();
        sfx[t] += add;
        __syncthreads();
    }
    unsigned krem = (unsigned)(*kptr);
    unsigned above = (t + 1 < 256) ? sfx[t + 1] : 0;
    if (above < krem && sfx[t] >= krem) {
        unsigned cum = above;
        int b = t * 16;
        for (int j = 15; j >= 0; --j) {
            unsigned cc = local[j];
            if (cum + cc >= krem) { b = t * 16 + j; break; }
            cum += cc;
        }
        sel[0] = krem - cum;
        sel[1] = ((unsigned)b) << 20;
    }
}

// ========== K7: compact candidates (from scores) ==========
__global__ void compact_kernel(const float4* __restrict__ scores4,
                               const unsigned* __restrict__ sel,
                               uint2* __restrict__ cand, unsigned* __restrict__ candCount,
                               int n4, int nnz) {
    unsigned pref = sel[1] >> 20;
    int tid = blockIdx.x * blockDim.x + threadIdx.x;
    int stride = gridDim.x * blockDim.x;
    int lane = threadIdx.x & 63;
    int niter = (n4 + stride - 1) / stride;
    for (int kk = 0; kk < niter; ++kk) {
        int i = tid + kk * stride;
        bool inb = (i < n4);
        float4 sv = make_float4(0.f, 0.f, 0.f, 0.f);
        if (inb) sv = scores4[i];
        unsigned bb[4] = {__float_as_uint(sv.x), __float_as_uint(sv.y),
                          __float_as_uint(sv.z), __float_as_uint(sv.w)};
        #pragma unroll
        for (int q = 0; q < 4; ++q) {
            bool pred = inb && ((bb[q] >> 20) == pref);
            unsigned long long mask = __ballot(pred);
            if (mask) {
                int leader = __ffsll(mask) - 1;
                unsigned base = 0;
                if (lane == leader) base = atomicAdd(candCount, (unsigned)__popcll(mask));
                base = __shfl(base, leader, 64);
                if (pred) {
                    unsigned rank = __popcll(mask & ((1ull << lane) - 1ull));
                    unsigned pos = base + rank;
                    if (pos < CAND_CAP) cand[pos] = make_uint2(bb[q], (unsigned)(i * 4 + q));
                }
            }
        }
    }
    for (int i = n4 * 4 + tid; i < nnz; i += stride) {
        unsigned b = __float_as_uint(((const float*)scores4)[i]);
        if ((b >> 20) == pref) {
            unsigned pos = atomicAdd(candCount, 1u);
            if (pos < CAND_CAP) cand[pos] = make_uint2(b, (unsigned)i);
        }
    }
}

// ========== K8: single-block selection among candidates ==========
__global__ __launch_bounds__(256) void select_small(const uint2* __restrict__ cand,
                            const unsigned* __restrict__ candCount,
                            unsigned* __restrict__ sel, unsigned* __restrict__ tieList) {
    __shared__ unsigned h2[4096];
    __shared__ unsigned sfx[256];
    __shared__ unsigned sB2, sKrem2, sT, sM;
    __shared__ unsigned h3[256];
    __shared__ unsigned ties[TIE_CAP];
    __shared__ unsigned tcnt;
    int t = threadIdx.x;
    unsigned nc = *candCount;
    int n = (nc < CAND_CAP) ? (int)nc : CAND_CAP;
    unsigned krem = sel[0];
    unsigned pref = sel[1];

    for (int j = t; j < 4096; j += 256) h2[j] = 0;
    if (t == 0) tcnt = 0;
    __syncthreads();
    for (int j = t; j < n; j += 256) atomicAdd(&h2[(cand[j].x >> 8) & 0xFFF], 1u);
    __syncthreads();

    unsigned local[16];
    unsigned s = 0;
    #pragma unroll
    for (int j = 0; j < 16; ++j) { local[j] = h2[t * 16 + j]; s += local[j]; }
    sfx[t] = s;
    __syncthreads();
    for (int off = 1; off < 256; off <<= 1) {
        unsigned add = (t + off < 256) ? sfx[t + off] : 0;
        __syncthreads();
        sfx[t] += add;
        __syncthreads();
    }
    {
        unsigned above = (t + 1 < 256) ? sfx[t + 1] : 0;
        if (above < krem && sfx[t] >= krem) {
            unsigned cum = above;
            int b = t * 16;
            for (int j = 15; j >= 0; --j) {
                unsigned cc = local[j];
                if (cum + cc >= krem) { b = t * 16 + j; break; }
                cum += cc;
            }
            sB2 = (unsigned)b;
            sKrem2 = krem - cum;
        }
    }
    __syncthreads();

    h3[t] = 0;
    __syncthreads();
    unsigned b2 = sB2;
    for (int j = t; j < n; j += 256) {
        unsigned x = cand[j].x;
        if (((x >> 8) & 0xFFF) == b2) atomicAdd(&h3[x & 0xFF], 1u);
    }
    __syncthreads();
    sfx[t] = h3[t];
    __syncthreads();
    for (int off = 1; off < 256; off <<= 1) {
        unsigned add = (t + off < 256) ? sfx[t + off] : 0;
        __syncthreads();
        sfx[t] += add;
        __syncthreads();
    }
    {
        unsigned krem2 = sKrem2;
        unsigned above = (t + 1 < 256) ? sfx[t + 1] : 0;
        if (above < krem2 && sfx[t] >= krem2) {
            sT = pref | (b2 << 8) | (unsigned)t;
            sM = krem2 - above;
        }
    }
    __syncthreads();

    unsigned T = sT;
    for (int j = t; j < n; j += 256) {
        if (cand[j].x == T) {
            unsigned p = atomicAdd(&tcnt, 1u);
            if (p < TIE_CAP) ties[p] = cand[j].y;
        }
    }
    __syncthreads();
    if (t == 0) {
        unsigned cnt = (tcnt < TIE_CAP) ? tcnt : TIE_CAP;
        for (unsigned a = 1; a < cnt; ++a) {
            unsigned key = ties[a];
            int bpos = (int)a - 1;
            while (bpos >= 0 && ties[bpos] > key) { ties[bpos + 1] = ties[bpos]; --bpos; }
            ties[bpos + 1] = key;
        }
        unsigned m = sM;
        if (m > cnt) m = cnt;
        sel[2] = T;
        sel[3] = m;
        for (unsigned j = 0; j < m; ++j) tieList[j] = ties[j];
    }
}

// ========== K9: per-bucket ssum/cnt/hsum from pairs -> eprob/esoft/ehard ==========
__global__ __launch_bounds__(256) void edge_final(const u64* __restrict__ pairs,
        const unsigned* __restrict__ bucketBase, const unsigned* __restrict__ sel,
        const unsigned* __restrict__ tieList,
        float* __restrict__ eprob, float* __restrict__ esoft, float* __restrict__ ehard,
        int nhe) {
    __shared__ float ss[256];
    __shared__ unsigned cc[256];
    __shared__ unsigned hh[256];
    __shared__ unsigned ties[TIE_CAP];
    unsigned T = sel[2];
    unsigned m = sel[3];
    if (m > TIE_CAP) m = TIE_CAP;
    int t = threadIdx.x;
    ss[t] = 0.f; cc[t] = 0u; hh[t] = 0u;
    for (int j = t; j < (int)m; j += 256) ties[j] = tieList[j];
    __syncthreads();
    int b = blockIdx.x;
    unsigned n0 = bucketBase[b], n1 = bucketBase[b + 1];
    for (unsigned j = n0 + t; j < n1; j += 256) {
        u64 p = pairs[j];
        unsigned el = (unsigned)(p >> 56);
        unsigned bits = (unsigned)(p >> 26) & 0x3FFFFFFFu;
        atomicAdd(&ss[el], __uint_as_float(bits));
        atomicAdd(&cc[el], 1u);
        bool keep = bits > T;
        if (bits == T) {
            unsigned idx = (unsigned)(p & 0x3FFFFFFu);
            int lo = 0, hi = (int)m - 1;
            keep = false;
            while (lo <= hi) {
                int mid = (lo + hi) >> 1;
                unsigned v = ties[mid];
                if (v == idx) { keep = true; break; }
                if (v < idx) lo = mid + 1; else hi = mid - 1;
            }
        }
        if (keep) atomicAdd(&hh[el], 1u);
    }
    __syncthreads();
    int e = b * 256 + t;
    if (e < nhe) {
        float c = fmaxf((float)cc[t], 1.0f);
        eprob[e] = ss[t] / c;
        esoft[e] = (float)hh[t] / c;
        ehard[e] = (hh[t] > 0) ? 1.0f : 0.0f;
    }
}

// ========== K10: hard/soft classification (overwrites pairs region; runs last) ==========
__global__ __launch_bounds__(256) void write_hard(const float4* __restrict__ scores4,
                           const unsigned* __restrict__ sel,
                           const unsigned* __restrict__ tieList,
                           float4* __restrict__ hard4, float4* __restrict__ soft4,
                           int n4, int nnz) {
    __shared__ unsigned ties[TIE_CAP];
    unsigned T = sel[2];
    unsigned m = sel[3];
    if (m > TIE_CAP) m = TIE_CAP;
    for (int j = threadIdx.x; j < (int)m; j += blockDim.x) ties[j] = tieList[j];
    __syncthreads();
    int tid = blockIdx.x * blockDim.x + threadIdx.x;
    int stride = gridDim.x * blockDim.x;
    for (int i = tid; i < n4; i += stride) {
        float4 sv = scores4[i];
        unsigned bb[4] = {__float_as_uint(sv.x), __float_as_uint(sv.y),
                          __float_as_uint(sv.z), __float_as_uint(sv.w)};
        float hv[4];
        #pragma unroll
        for (int q = 0; q < 4; ++q) {
            bool keep = (bb[q] > T);
            if (bb[q] == T) {
                unsigned idx = (unsigned)(i * 4 + q);
                int lo = 0, hi = (int)m - 1;
                keep = false;
                while (lo <= hi) {
                    int mid = (lo + hi) >> 1;
                    unsigned v = ties[mid];
                    if (v == idx) { keep = true; break; }
                    if (v < idx) lo = mid + 1; else hi = mid - 1;
                }
            }
            hv[q] = keep ? 1.0f : 0.0f;
        }
        float4 outv = make_float4(hv[0], hv[1], hv[2], hv[3]);
        hard4[i] = outv;
        soft4[i] = outv;
    }
    const float* sc = (const float*)scores4;
    float* hard = (float*)hard4;
    float* soft = (float*)soft4;
    for (int i = n4 * 4 + tid; i < nnz; i += stride) {
        unsigned b = __float_as_uint(sc[i]);
        bool keep = (b > T);
        if (b == T) {
            unsigned idx = (unsigned)i;
            int lo = 0, hi = (int)m - 1;
            keep = false;
            while (lo <= hi) {
                int mid = (lo + hi) >> 1;
                unsigned v = ties[mid];
                if (v == idx) { keep = true; break; }
                if (v < idx) lo = mid + 1; else hi = mid - 1;
            }
        }
        float hvv = keep ? 1.0f : 0.0f;
        hard[i] = hvv;
        soft[i] = hvv;
    }
}

extern "C" void kernel_launch(void* const* d_in, const int* in_sizes, int n_in,
                              void* d_out, int out_size, void* d_ws, size_t ws_size,
                              hipStream_t stream) {
    const float* x        = (const float*)d_in[0];
    const float* Wm       = (const float*)d_in[1];
    const float* ef       = (const float*)d_in[2];
    const int*   V_idx    = (const int*)d_in[3];
    const int*   E_idx    = (const int*)d_in[4];
    const int*   edge_ids = (const int*)d_in[5];
    const int*   kptr     = (const int*)d_in[6];

    const int nnz     = in_sizes[3];
    const int nhe     = in_sizes[5];
    const int n_nodes = in_sizes[0] / FEAT;
    const int nb      = (nhe + 255) >> 8;

    float* out    = (float*)d_out;
    float* scores = out;
    float* soft   = out + (size_t)nnz;
    float* hard   = out + 2 * (size_t)nnz;
    float* eprob  = out + 3 * (size_t)nnz;
    float* esoft  = eprob + nhe;
    float* ehard  = esoft + nhe;

    // vlist/pairs share soft+hard (nnz u64); bucket_score converts vlist->pairs
    // in place; edge_final consumes pairs; write_hard overwrites region last.
    u64*   vlist = (u64*)soft;
    // cand lives in eprob+esoft+ehard (1 MB <= 1.43 MB); consumed by select_small
    // BEFORE edge_final writes eprob/esoft/ehard.
    uint2* cand  = (uint2*)eprob;

    // ---- aux zone in d_ws ----
    char* w = (char*)d_ws;
    unsigned* hist1      = (unsigned*)w;               // 4096  (zeroed)
    unsigned* bucketCnt  = hist1 + 4096;               // NBK_MAX (zeroed)
    unsigned* candCount  = bucketCnt + NBK_MAX;        // 1 (zeroed)
    unsigned* ticket1    = candCount + 1;              // 1 (zeroed)
    unsigned* sel        = ticket1 + 1;                // 8
    unsigned* tieList    = sel + 8;                    // TIE_CAP
    unsigned* bucketBase = tieList + TIE_CAP;          // NBK_MAX+1
    unsigned* cursor     = bucketBase + NBK_MAX + 1;   // NBK_MAX
    char* auxEnd = (char*)(cursor + NBK_MAX);
    size_t auxAligned = (((size_t)(auxEnd - w)) + 255) & ~(size_t)255;
    size_t zeroBytes = (size_t)(4096 + NBK_MAX + 2) * sizeof(unsigned);

    size_t ef2Bytes  = (size_t)nhe * RANKK * sizeof(float);
    size_t projBytes = (size_t)n_nodes * RANKK * sizeof(float);

    bool wsBig = (ws_size >= auxAligned + ef2Bytes + projBytes);
    float* ef2;
    float* proj;
    if (wsBig) {
        ef2  = (float*)(w + auxAligned);
        proj = (float*)(w + auxAligned + ef2Bytes);
    } else {
        // fallback: ef2/proj in hard region (consumed by score before pair_build
        // scatters pairs over soft+hard) — r4-proven layout
        ef2  = hard;
        proj = hard + (size_t)nhe * RANKK;
    }

    hipMemsetAsync(w, 0, zeroBytes, stream);

    ehist_scan<<<128, 256, 0, stream>>>(E_idx, bucketCnt, bucketBase, cursor, ticket1, nnz);

    int G = (nhe * 4 + 255) / 256;
    int P = (n_nodes + PRJ_NODES - 1) / PRJ_NODES;
    prep_combo<<<G + P, 256, 0, stream>>>((const float4*)ef, edge_ids, (float4*)ef2, nhe,
                                          x, Wm, proj, n_nodes, G);

    int nChunks = (nnz + PB_CHUNK - 1) / PB_CHUNK;
    if (wsBig) {
        // primary: sort -> bucket-ordered score with ef2 tile in LDS
        sort_kernel<<<nChunks, 256, 0, stream>>>(V_idx, E_idx, vlist, cursor, nnz, nb);
        bucket_score<<<nb * SPLIT, 256, 0, stream>>>(
            (const float4*)proj, (const float4*)ef2, bucketBase, vlist, scores, nhe);
    } else {
        // fallback: linear score + pair_build (r4-proven)
        score_linear<<<2048, 256, 0, stream>>>(
            (const float4*)proj, (const float4*)ef2, V_idx, E_idx, scores, nnz);
        pair_build<<<nChunks, 256, 0, stream>>>(E_idx, scores, vlist, cursor, nnz, nb);
    }

    int n4 = nnz / 4;
    hist1_kernel<<<128, 256, 0, stream>>>((const float4*)scores, hist1, n4, nnz);
    scan1_kernel<<<1, 256, 0, stream>>>(hist1, sel, kptr);
    compact_kernel<<<1024, 256, 0, stream>>>(
        (const float4*)scores, sel, cand, candCount, n4, nnz);
    select_small<<<1, 256, 0, stream>>>(cand, candCount, sel, tieList);

    edge_final<<<nb, 256, 0, stream>>>(vlist, bucketBase, sel, tieList,
                                       eprob, esoft, ehard, nhe);
    write_hard<<<1024, 256, 0, stream>>>(
        (const float4*)scores, sel, tieList, (float4*)hard, (float4*)soft, n4, nnz);
}

// Round 9
// 472.556 us; speedup vs baseline: 1.2072x; 1.0052x over previous
//
#include <hip/hip_runtime.h>
#include <math.h>

#define FEAT 256
#define RANKK 16
#define CAND_CAP 131072
#define TIE_CAP 2048
#define NBK_MAX 512   // max buckets (nhe/256)
#define PB_CHUNK 8192
#define SPLIT 4       // blocks per bucket in bucket_score
#define PRJ_NODES 64  // nodes per proj block (2n x 2r register tiling)

typedef unsigned long long u64;

static __device__ __forceinline__ u64 pack_pair(unsigned e_low, unsigned bits, unsigned idx) {
    // [63:56]=e&255, [55:26]=score bits (<2^30 since score<=1.0f), [25:0]=idx
    return ((u64)e_low << 56) | ((u64)bits << 26) | (u64)idx;
}

// vlist entry: [63:40]=v (24b), [31:8]=idx (24b), [7:0]=e&255
static __device__ __forceinline__ u64 pack_v(unsigned v, unsigned idx, unsigned e_low) {
    return ((u64)v << 40) | ((u64)idx << 8) | (u64)e_low;
}

// ========== K1: bucket histogram of E_idx>>8 + last-block exclusive scan ==========
__global__ __launch_bounds__(256) void ehist_scan(const int* __restrict__ E_idx,
        unsigned* __restrict__ bucketCnt, unsigned* __restrict__ bucketBase,
        unsigned* __restrict__ cursor, unsigned* __restrict__ ticket, int nnz) {
    __shared__ unsigned h[NBK_MAX];
    __shared__ unsigned ps[256];
    __shared__ unsigned isLast;
    int t = threadIdx.x;
    for (int j = t; j < NBK_MAX; j += 256) h[j] = 0;
    __syncthreads();
    for (int i = blockIdx.x * 256 + t; i < nnz; i += gridDim.x * 256)
        atomicAdd(&h[((unsigned)E_idx[i]) >> 8], 1u);
    __syncthreads();
    for (int j = t; j < NBK_MAX; j += 256)
        if (h[j]) atomicAdd(&bucketCnt[j], h[j]);
    __threadfence();
    if (t == 0) isLast = (atomicAdd(ticket, 1u) == gridDim.x - 1) ? 1u : 0u;
    __syncthreads();
    if (!isLast) return;
    unsigned a0 = atomicAdd(&bucketCnt[2 * t], 0u);
    unsigned a1 = atomicAdd(&bucketCnt[2 * t + 1], 0u);
    unsigned pairsum = a0 + a1;
    ps[t] = pairsum;
    __syncthreads();
    for (int off = 1; off < 256; off <<= 1) {
        unsigned v = (t >= off) ? ps[t - off] : 0u;
        __syncthreads();
        ps[t] += v;
        __syncthreads();
    }
    unsigned excl = ps[t] - pairsum;
    bucketBase[2 * t] = excl;           cursor[2 * t] = excl;
    bucketBase[2 * t + 1] = excl + a0;  cursor[2 * t + 1] = excl + a0;
    if (t == 255) bucketBase[NBK_MAX] = ps[255];   // == nnz
}

// ========== K2: gather_ef + proj combo (proj: 2n x 2r register tiling, K-chunked) ==========
__global__ __launch_bounds__(256) void prep_combo(
        const float4* __restrict__ ef, const int* __restrict__ edge_ids,
        float4* __restrict__ ef2, int nhe,
        const float* __restrict__ x, const float* __restrict__ Wm,
        float* __restrict__ proj, int n_nodes, int G) {
    __shared__ float Ws[RANKK][FEAT + 4];        // 16.6 KB, full 256-wide
    __shared__ float Xs[PRJ_NODES][128 + 4];     // 33.8 KB, one 128-feat chunk
    if ((int)blockIdx.x < G) {
        int t = blockIdx.x * 256 + threadIdx.x;
        if (t < nhe * 4) {
            int e = t >> 2, c = t & 3;
            ef2[(size_t)e * 4 + c] = ef[(size_t)edge_ids[e] * 4 + c];
        }
        return;
    }
    int pb = blockIdx.x - G;
    const float4* x4 = (const float4*)x;
    const float4* w4 = (const float4*)Wm;
    // stage full W (16 x 64 float4)
    for (int i = threadIdx.x; i < RANKK * 64; i += 256) {
        int r = i >> 6, c4 = i & 63;
        *(float4*)&Ws[r][c4 * 4] = w4[(size_t)r * 64 + c4];
    }
    int nodeBase = pb * PRJ_NODES;
    int np = threadIdx.x >> 3;       // 0..31
    int rp = threadIdx.x & 7;        // 0..7
    int n0 = np * 2, r0 = rp * 2;
    double a00 = 0.0, a01 = 0.0, a10 = 0.0, a11 = 0.0;
    for (int chunk = 0; chunk < 2; ++chunk) {
        __syncthreads();   // chunk0: covers W staging; chunk1: protects Xs reuse
        for (int i = threadIdx.x; i < PRJ_NODES * 32; i += 256) {
            int row = i >> 5, c4 = i & 31;
            int node = nodeBase + row;
            float4 v = make_float4(0.f, 0.f, 0.f, 0.f);
            if (node < n_nodes) v = x4[(size_t)node * 64 + chunk * 32 + c4];
            *(float4*)&Xs[row][c4 * 4] = v;
        }
        __syncthreads();
        int jw = chunk * 128;
        #pragma unroll 8
        for (int j4 = 0; j4 < 32; ++j4) {
            float4 xa = *(const float4*)&Xs[n0][j4 * 4];
            float4 xb = *(const float4*)&Xs[n0 + 1][j4 * 4];
            float4 wa = *(const float4*)&Ws[r0][jw + j4 * 4];
            float4 wb = *(const float4*)&Ws[r0 + 1][jw + j4 * 4];
            a00 += (double)xa.x * wa.x + (double)xa.y * wa.y + (double)xa.z * wa.z + (double)xa.w * wa.w;
            a01 += (double)xa.x * wb.x + (double)xa.y * wb.y + (double)xa.z * wb.z + (double)xa.w * wb.w;
            a10 += (double)xb.x * wa.x + (double)xb.y * wa.y + (double)xb.z * wa.z + (double)xb.w * wa.w;
            a11 += (double)xb.x * wb.x + (double)xb.y * wb.y + (double)xb.z * wb.z + (double)xb.w * wb.w;
        }
    }
    int nodeA = nodeBase + n0;
    int nodeB = nodeA + 1;
    if (nodeA < n_nodes) {
        proj[(size_t)nodeA * RANKK + r0]     = (float)a00;
        proj[(size_t)nodeA * RANKK + r0 + 1] = (float)a01;
    }
    if (nodeB < n_nodes) {
        proj[(size_t)nodeB * RANKK + r0]     = (float)a10;
        proj[(size_t)nodeB * RANKK + r0 + 1] = (float)a11;
    }
}

// ========== K3: sort incidences into bucket order (block-aggregated cursor alloc) ==========
__global__ __launch_bounds__(256) void sort_kernel(const int* __restrict__ V_idx,
        const int* __restrict__ E_idx, u64* __restrict__ vlist,
        unsigned* __restrict__ cursor, int nnz, int nb) {
    __shared__ unsigned bh[NBK_MAX];
    int t = threadIdx.x;
    for (int j = t; j < NBK_MAX; j += 256) bh[j] = 0;
    __syncthreads();
    int base = blockIdx.x * PB_CHUNK;
    int nE = nnz - base;
    if (nE > PB_CHUNK) nE = PB_CHUNK;
    for (int o = t; o < nE; o += 256)
        atomicAdd(&bh[((unsigned)E_idx[base + o]) >> 8], 1u);
    __syncthreads();
    for (int b = t; b < nb; b += 256) {
        unsigned c = bh[b];
        bh[b] = c ? atomicAdd(&cursor[b], c) : 0u;
    }
    __syncthreads();
    for (int o = t; o < nE; o += 256) {
        int i = base + o;
        unsigned e = (unsigned)E_idx[i];
        unsigned v = (unsigned)V_idx[i];
        unsigned pos = atomicAdd(&bh[e >> 8], 1u);
        vlist[pos] = pack_v(v, (unsigned)i, e & 255u);
    }
}

// ========== K4a (primary): bucket-ordered score; ef2 tile in LDS; pairs in place ==========
__global__ __launch_bounds__(256) void bucket_score(
        const float4* __restrict__ proj4, const float4* __restrict__ ef4,
        const unsigned* __restrict__ bucketBase, u64* __restrict__ list,
        float* __restrict__ scores, int nhe) {
    __shared__ float efs[256][20];
    int t = threadIdx.x;
    int b = blockIdx.x >> 2;
    int part = blockIdx.x & (SPLIT - 1);
    for (int jj = t; jj < 1024; jj += 256) {
        int edge = (b << 8) + (jj >> 2);
        if (edge < nhe) {
            float4 v = ef4[(size_t)edge * 4 + (jj & 3)];
            *(float4*)&efs[jj >> 2][(jj & 3) * 4] = v;
        }
    }
    __syncthreads();
    unsigned n0 = bucketBase[b], n1 = bucketBase[b + 1];
    #pragma unroll 2
    for (unsigned j = n0 + (part << 8) + t; j < n1; j += SPLIT * 256) {
        u64 p = list[j];
        unsigned v   = (unsigned)(p >> 40);
        unsigned idx = (unsigned)(p >> 8) & 0xFFFFFFu;
        unsigned el  = (unsigned)(p & 255u);
        float4 p0 = proj4[(size_t)v * 4 + 0];
        float4 p1 = proj4[(size_t)v * 4 + 1];
        float4 p2 = proj4[(size_t)v * 4 + 2];
        float4 p3 = proj4[(size_t)v * 4 + 3];
        float4 f0 = *(const float4*)&efs[el][0];
        float4 f1 = *(const float4*)&efs[el][4];
        float4 f2 = *(const float4*)&efs[el][8];
        float4 f3 = *(const float4*)&efs[el][12];
        double acc = (double)p0.x * f0.x + (double)p0.y * f0.y + (double)p0.z * f0.z + (double)p0.w * f0.w
                   + (double)p1.x * f1.x + (double)p1.y * f1.y + (double)p1.z * f1.z + (double)p1.w * f1.w
                   + (double)p2.x * f2.x + (double)p2.y * f2.y + (double)p2.z * f2.z + (double)p2.w * f2.w
                   + (double)p3.x * f3.x + (double)p3.y * f3.y + (double)p3.z * f3.z + (double)p3.w * f3.w;
        float s = (float)(1.0 / (1.0 + exp(-acc)));
        scores[idx] = s;
        list[j] = pack_pair(el, __float_as_uint(s), idx);
    }
}

// ========== K4b (fallback): linear score ==========
__global__ __launch_bounds__(256) void score_linear(
        const float4* __restrict__ proj4, const float4* __restrict__ ef4,
        const int* __restrict__ V_idx, const int* __restrict__ E_idx,
        float* __restrict__ scores, int nnz) {
    int stride = gridDim.x * blockDim.x;
    #pragma unroll 2
    for (int i = blockIdx.x * blockDim.x + threadIdx.x; i < nnz; i += stride) {
        int v = V_idx[i], e = E_idx[i];
        float4 p0 = proj4[(size_t)v * 4 + 0];
        float4 p1 = proj4[(size_t)v * 4 + 1];
        float4 p2 = proj4[(size_t)v * 4 + 2];
        float4 p3 = proj4[(size_t)v * 4 + 3];
        float4 f0 = ef4[(size_t)e * 4 + 0];
        float4 f1 = ef4[(size_t)e * 4 + 1];
        float4 f2 = ef4[(size_t)e * 4 + 2];
        float4 f3 = ef4[(size_t)e * 4 + 3];
        double acc = (double)p0.x * f0.x + (double)p0.y * f0.y + (double)p0.z * f0.z + (double)p0.w * f0.w
                   + (double)p1.x * f1.x + (double)p1.y * f1.y + (double)p1.z * f1.z + (double)p1.w * f1.w
                   + (double)p2.x * f2.x + (double)p2.y * f2.y + (double)p2.z * f2.z + (double)p2.w * f2.w
                   + (double)p3.x * f3.x + (double)p3.y * f3.y + (double)p3.z * f3.z + (double)p3.w * f3.w;
        scores[i] = (float)(1.0 / (1.0 + exp(-acc)));
    }
}

// ========== K4c (fallback): pair_build ==========
__global__ __launch_bounds__(256) void pair_build(const int* __restrict__ E_idx,
        const float* __restrict__ scores, u64* __restrict__ pairs,
        unsigned* __restrict__ cursor, int nnz, int nb) {
    __shared__ unsigned bh[NBK_MAX];
    for (int t = threadIdx.x; t < NBK_MAX; t += 256) bh[t] = 0;
    __syncthreads();
    int base = blockIdx.x * PB_CHUNK;
    int nE = nnz - base;
    if (nE > PB_CHUNK) nE = PB_CHUNK;
    for (int o = threadIdx.x; o < nE; o += 256)
        atomicAdd(&bh[((unsigned)E_idx[base + o]) >> 8], 1u);
    __syncthreads();
    for (int b = threadIdx.x; b < nb; b += 256) {
        unsigned c = bh[b];
        bh[b] = c ? atomicAdd(&cursor[b], c) : 0u;
    }
    __syncthreads();
    for (int o = threadIdx.x; o < nE; o += 256) {
        int i = base + o;
        unsigned e = (unsigned)E_idx[i];
        unsigned bits = __float_as_uint(scores[i]);
        unsigned pos = atomicAdd(&bh[e >> 8], 1u);
        pairs[pos] = pack_pair(e & 255u, bits, (unsigned)i);
    }
}

// ========== K5: level-1 histogram over scores (hot bins in regs) ==========
__global__ void hist1_kernel(const float4* __restrict__ scores4, unsigned* __restrict__ hist1g,
                             int n4, int nnz) {
    __shared__ unsigned h[4096];
    for (int t = threadIdx.x; t < 4096; t += blockDim.x) h[t] = 0;
    __syncthreads();
    unsigned r1016 = 0, r1015 = 0, r0 = 0;
    int stride = gridDim.x * blockDim.x;
    for (int i = blockIdx.x * blockDim.x + threadIdx.x; i < n4; i += stride) {
        float4 sv = scores4[i];
        unsigned bb[4] = {__float_as_uint(sv.x), __float_as_uint(sv.y),
                          __float_as_uint(sv.z), __float_as_uint(sv.w)};
        #pragma unroll
        for (int q = 0; q < 4; ++q) {
            unsigned b = bb[q] >> 20;
            if (b == 1016) ++r1016;
            else if (b == 1015) ++r1015;
            else if (b == 0) ++r0;
            else atomicAdd(&h[b], 1u);
        }
    }
    for (int i = n4 * 4 + blockIdx.x * blockDim.x + threadIdx.x; i < nnz; i += stride) {
        unsigned b = __float_as_uint(((const float*)scores4)[i]) >> 20;
        if (b == 1016) ++r1016;
        else if (b == 1015) ++r1015;
        else if (b == 0) ++r0;
        else atomicAdd(&h[b], 1u);
    }
    if (r1016) atomicAdd(&h[1016], r1016);
    if (r1015) atomicAdd(&h[1015], r1015);
    if (r0) atomicAdd(&h[0], r0);
    __syncthreads();
    for (int t = threadIdx.x; t < 4096; t += blockDim.x)
        if (h[t]) atomicAdd(&hist1g[t], h[t]);
}

// ========== K6: parallel level-1 suffix scan ==========
__global__ void scan1_kernel(const unsigned* __restrict__ hist,
                             unsigned* __restrict__ sel, const int* __restrict__ kptr) {
    __shared__ unsigned sfx[256];
    int t = threadIdx.x;
    unsigned local[16];
    unsigned s = 0;
    #pragma unroll
    for (int j = 0; j < 16; ++j) { local[j] = hist[t * 16 + j]; s += local[j]; }
    sfx[t] = s;
    __syncthreads();
    for (int off = 1; off < 256; off <<= 1) {
        unsigned add = (t + off < 256) ? sfx[t + off] : 0;
        __syncthreads();
        sfx[t] += add;
        __syncthreads();
    }
    unsigned krem = (unsigned)(*kptr);
    unsigned above = (t + 1 < 256) ? sfx[t + 1] : 0;
    if (above < krem && sfx[t] >= krem) {
        unsigned cum = above;
        int b = t * 16;
        for (int j = 15; j >= 0; --j) {
            unsigned cc = local[j];
            if (cum + cc >= krem) { b = t * 16 + j; break; }
            cum += cc;
        }
        sel[0] = krem - cum;
        sel[1] = ((unsigned)b) << 20;
    }
}

// ========== K7: compact candidates ==========
__global__ void compact_kernel(const float4* __restrict__ scores4,
                               const unsigned* __restrict__ sel,
                               uint2* __restrict__ cand, unsigned* __restrict__ candCount,
                               int n4, int nnz) {
    unsigned pref = sel[1] >> 20;
    int tid = blockIdx.x * blockDim.x + threadIdx.x;
    int stride = gridDim.x * blockDim.x;
    int lane = threadIdx.x & 63;
    int niter = (n4 + stride - 1) / stride;
    for (int kk = 0; kk < niter; ++kk) {
        int i = tid + kk * stride;
        bool inb = (i < n4);
        float4 sv = make_float4(0.f, 0.f, 0.f, 0.f);
        if (inb) sv = scores4[i];
        unsigned bb[4] = {__float_as_uint(sv.x), __float_as_uint(sv.y),
                          __float_as_uint(sv.z), __float_as_uint(sv.w)};
        #pragma unroll
        for (int q = 0; q < 4; ++q) {
            bool pred = inb && ((bb[q] >> 20) == pref);
            unsigned long long mask = __ballot(pred);
            if (mask) {
                int leader = __ffsll(mask) - 1;
                unsigned base = 0;
                if (lane == leader) base = atomicAdd(candCount, (unsigned)__popcll(mask));
                base = __shfl(base, leader, 64);
                if (pred) {
                    unsigned rank = __popcll(mask & ((1ull << lane) - 1ull));
                    unsigned pos = base + rank;
                    if (pos < CAND_CAP) cand[pos] = make_uint2(bb[q], (unsigned)(i * 4 + q));
                }
            }
        }
    }
    for (int i = n4 * 4 + tid; i < nnz; i += stride) {
        unsigned b = __float_as_uint(((const float*)scores4)[i]);
        if ((b >> 20) == pref) {
            unsigned pos = atomicAdd(candCount, 1u);
            if (pos < CAND_CAP) cand[pos] = make_uint2(b, (unsigned)i);
        }
    }
}

// ========== K8: single-block selection among candidates ==========
__global__ __launch_bounds__(256) void select_small(const uint2* __restrict__ cand,
                            const unsigned* __restrict__ candCount,
                            unsigned* __restrict__ sel, unsigned* __restrict__ tieList) {
    __shared__ unsigned h2[4096];
    __shared__ unsigned sfx[256];
    __shared__ unsigned sB2, sKrem2, sT, sM;
    __shared__ unsigned h3[256];
    __shared__ unsigned ties[TIE_CAP];
    __shared__ unsigned tcnt;
    int t = threadIdx.x;
    unsigned nc = *candCount;
    int n = (nc < CAND_CAP) ? (int)nc : CAND_CAP;
    unsigned krem = sel[0];
    unsigned pref = sel[1];

    for (int j = t; j < 4096; j += 256) h2[j] = 0;
    if (t == 0) tcnt = 0;
    __syncthreads();
    for (int j = t; j < n; j += 256) atomicAdd(&h2[(cand[j].x >> 8) & 0xFFF], 1u);
    __syncthreads();

    unsigned local[16];
    unsigned s = 0;
    #pragma unroll
    for (int j = 0; j < 16; ++j) { local[j] = h2[t * 16 + j]; s += local[j]; }
    sfx[t] = s;
    __syncthreads();
    for (int off = 1; off < 256; off <<= 1) {
        unsigned add = (t + off < 256) ? sfx[t + off] : 0;
        __syncthreads();
        sfx[t] += add;
        __syncthreads();
    }
    {
        unsigned above = (t + 1 < 256) ? sfx[t + 1] : 0;
        if (above < krem && sfx[t] >= krem) {
            unsigned cum = above;
            int b = t * 16;
            for (int j = 15; j >= 0; --j) {
                unsigned cc = local[j];
                if (cum + cc >= krem) { b = t * 16 + j; break; }
                cum += cc;
            }
            sB2 = (unsigned)b;
            sKrem2 = krem - cum;
        }
    }
    __syncthreads();

    h3[t] = 0;
    __syncthreads();
    unsigned b2 = sB2;
    for (int j = t; j < n; j += 256) {
        unsigned x = cand[j].x;
        if (((x >> 8) & 0xFFF) == b2) atomicAdd(&h3[x & 0xFF], 1u);
    }
    __syncthreads();
    sfx[t] = h3[t];
    __syncthreads();
    for (int off = 1; off < 256; off <<= 1) {
        unsigned add = (t + off < 256) ? sfx[t + off] : 0;
        __syncthreads();
        sfx[t] += add;
        __syncthreads();
    }
    {
        unsigned krem2 = sKrem2;
        unsigned above = (t + 1 < 256) ? sfx[t + 1] : 0;
        if (above < krem2 && sfx[t] >= krem2) {
            sT = pref | (b2 << 8) | (unsigned)t;
            sM = krem2 - above;
        }
    }
    __syncthreads();

    unsigned T = sT;
    for (int j = t; j < n; j += 256) {
        if (cand[j].x == T) {
            unsigned p = atomicAdd(&tcnt, 1u);
            if (p < TIE_CAP) ties[p] = cand[j].y;
        }
    }
    __syncthreads();
    if (t == 0) {
        unsigned cnt = (tcnt < TIE_CAP) ? tcnt : TIE_CAP;
        for (unsigned a = 1; a < cnt; ++a) {
            unsigned key = ties[a];
            int bpos = (int)a - 1;
            while (bpos >= 0 && ties[bpos] > key) { ties[bpos + 1] = ties[bpos]; --bpos; }
            ties[bpos + 1] = key;
        }
        unsigned m = sM;
        if (m > cnt) m = cnt;
        sel[2] = T;
        sel[3] = m;
        for (unsigned j = 0; j < m; ++j) tieList[j] = ties[j];
    }
}

// ========== K9: per-bucket ssum/cnt/hsum from pairs -> eprob/esoft/ehard ==========
__global__ __launch_bounds__(256) void edge_final(const u64* __restrict__ pairs,
        const unsigned* __restrict__ bucketBase, const unsigned* __restrict__ sel,
        const unsigned* __restrict__ tieList,
        float* __restrict__ eprob, float* __restrict__ esoft, float* __restrict__ ehard,
        int nhe) {
    __shared__ float ss[256];
    __shared__ unsigned cc[256];
    __shared__ unsigned hh[256];
    __shared__ unsigned ties[TIE_CAP];
    unsigned T = sel[2];
    unsigned m = sel[3];
    if (m > TIE_CAP) m = TIE_CAP;
    int t = threadIdx.x;
    ss[t] = 0.f; cc[t] = 0u; hh[t] = 0u;
    for (int j = t; j < (int)m; j += 256) ties[j] = tieList[j];
    __syncthreads();
    int b = blockIdx.x;
    unsigned n0 = bucketBase[b], n1 = bucketBase[b + 1];
    for (unsigned j = n0 + t; j < n1; j += 256) {
        u64 p = pairs[j];
        unsigned el = (unsigned)(p >> 56);
        unsigned bits = (unsigned)(p >> 26) & 0x3FFFFFFFu;
        atomicAdd(&ss[el], __uint_as_float(bits));
        atomicAdd(&cc[el], 1u);
        bool keep = bits > T;
        if (bits == T) {
            unsigned idx = (unsigned)(p & 0x3FFFFFFu);
            int lo = 0, hi = (int)m - 1;
            keep = false;
            while (lo <= hi) {
                int mid = (lo + hi) >> 1;
                unsigned v = ties[mid];
                if (v == idx) { keep = true; break; }
                if (v < idx) lo = mid + 1; else hi = mid - 1;
            }
        }
        if (keep) atomicAdd(&hh[el], 1u);
    }
    __syncthreads();
    int e = b * 256 + t;
    if (e < nhe) {
        float c = fmaxf((float)cc[t], 1.0f);
        eprob[e] = ss[t] / c;
        esoft[e] = (float)hh[t] / c;
        ehard[e] = (hh[t] > 0) ? 1.0f : 0.0f;
    }
}

// ========== K10: hard/soft classification (overwrites pairs region; runs last) ==========
__global__ __launch_bounds__(256) void write_hard(const float4* __restrict__ scores4,
                           const unsigned* __restrict__ sel,
                           const unsigned* __restrict__ tieList,
                           float4* __restrict__ hard4, float4* __restrict__ soft4,
                           int n4, int nnz) {
    __shared__ unsigned ties[TIE_CAP];
    unsigned T = sel[2];
    unsigned m = sel[3];
    if (m > TIE_CAP) m = TIE_CAP;
    for (int j = threadIdx.x; j < (int)m; j += blockDim.x) ties[j] = tieList[j];
    __syncthreads();
    int tid = blockIdx.x * blockDim.x + threadIdx.x;
    int stride = gridDim.x * blockDim.x;
    for (int i = tid; i < n4; i += stride) {
        float4 sv = scores4[i];
        unsigned bb[4] = {__float_as_uint(sv.x), __float_as_uint(sv.y),
                          __float_as_uint(sv.z), __float_as_uint(sv.w)};
        float hv[4];
        #pragma unroll
        for (int q = 0; q < 4; ++q) {
            bool keep = (bb[q] > T);
            if (bb[q] == T) {
                unsigned idx = (unsigned)(i * 4 + q);
                int lo = 0, hi = (int)m - 1;
                keep = false;
                while (lo <= hi) {
                    int mid = (lo + hi) >> 1;
                    unsigned v = ties[mid];
                    if (v == idx) { keep = true; break; }
                    if (v < idx) lo = mid + 1; else hi = mid - 1;
                }
            }
            hv[q] = keep ? 1.0f : 0.0f;
        }
        float4 outv = make_float4(hv[0], hv[1], hv[2], hv[3]);
        hard4[i] = outv;
        soft4[i] = outv;
    }
    const float* sc = (const float*)scores4;
    float* hard = (float*)hard4;
    float* soft = (float*)soft4;
    for (int i = n4 * 4 + tid; i < nnz; i += stride) {
        unsigned b = __float_as_uint(sc[i]);
        bool keep = (b > T);
        if (b == T) {
            unsigned idx = (unsigned)i;
            int lo = 0, hi = (int)m - 1;
            keep = false;
            while (lo <= hi) {
                int mid = (lo + hi) >> 1;
                unsigned v = ties[mid];
                if (v == idx) { keep = true; break; }
                if (v < idx) lo = mid + 1; else hi = mid - 1;
            }
        }
        float hvv = keep ? 1.0f : 0.0f;
        hard[i] = hvv;
        soft[i] = hvv;
    }
}

extern "C" void kernel_launch(void* const* d_in, const int* in_sizes, int n_in,
                              void* d_out, int out_size, void* d_ws, size_t ws_size,
                              hipStream_t stream) {
    const float* x        = (const float*)d_in[0];
    const float* Wm       = (const float*)d_in[1];
    const float* ef       = (const float*)d_in[2];
    const int*   V_idx    = (const int*)d_in[3];
    const int*   E_idx    = (const int*)d_in[4];
    const int*   edge_ids = (const int*)d_in[5];
    const int*   kptr     = (const int*)d_in[6];

    const int nnz     = in_sizes[3];
    const int nhe     = in_sizes[5];
    const int n_nodes = in_sizes[0] / FEAT;
    const int nb      = (nhe + 255) >> 8;

    float* out    = (float*)d_out;
    float* scores = out;
    float* soft   = out + (size_t)nnz;
    float* hard   = out + 2 * (size_t)nnz;
    float* eprob  = out + 3 * (size_t)nnz;
    float* esoft  = eprob + nhe;
    float* ehard  = esoft + nhe;

    u64*   vlist = (u64*)soft;      // vlist/pairs in soft+hard; write_hard overwrites last
    uint2* cand  = (uint2*)eprob;   // consumed by select_small before edge_final writes

    // ---- aux zone in d_ws ----
    char* w = (char*)d_ws;
    unsigned* hist1      = (unsigned*)w;               // 4096  (zeroed)
    unsigned* bucketCnt  = hist1 + 4096;               // NBK_MAX (zeroed)
    unsigned* candCount  = bucketCnt + NBK_MAX;        // 1 (zeroed)
    unsigned* ticket1    = candCount + 1;              // 1 (zeroed)
    unsigned* sel        = ticket1 + 1;                // 8
    unsigned* tieList    = sel + 8;                    // TIE_CAP
    unsigned* bucketBase = tieList + TIE_CAP;          // NBK_MAX+1
    unsigned* cursor     = bucketBase + NBK_MAX + 1;   // NBK_MAX
    char* auxEnd = (char*)(cursor + NBK_MAX);
    size_t auxAligned = (((size_t)(auxEnd - w)) + 255) & ~(size_t)255;
    size_t zeroBytes = (size_t)(4096 + NBK_MAX + 2) * sizeof(unsigned);

    size_t ef2Bytes  = (size_t)nhe * RANKK * sizeof(float);
    size_t projBytes = (size_t)n_nodes * RANKK * sizeof(float);

    bool wsBig = (ws_size >= auxAligned + ef2Bytes + projBytes);
    float* ef2;
    float* proj;
    if (wsBig) {
        ef2  = (float*)(w + auxAligned);
        proj = (float*)(w + auxAligned + ef2Bytes);
    } else {
        ef2  = hard;
        proj = hard + (size_t)nhe * RANKK;
    }

    hipMemsetAsync(w, 0, zeroBytes, stream);

    ehist_scan<<<128, 256, 0, stream>>>(E_idx, bucketCnt, bucketBase, cursor, ticket1, nnz);

    int G = (nhe * 4 + 255) / 256;
    int P = (n_nodes + PRJ_NODES - 1) / PRJ_NODES;
    prep_combo<<<G + P, 256, 0, stream>>>((const float4*)ef, edge_ids, (float4*)ef2, nhe,
                                          x, Wm, proj, n_nodes, G);

    int nChunks = (nnz + PB_CHUNK - 1) / PB_CHUNK;
    if (wsBig) {
        sort_kernel<<<nChunks, 256, 0, stream>>>(V_idx, E_idx, vlist, cursor, nnz, nb);
        bucket_score<<<nb * SPLIT, 256, 0, stream>>>(
            (const float4*)proj, (const float4*)ef2, bucketBase, vlist, scores, nhe);
    } else {
        score_linear<<<2048, 256, 0, stream>>>(
            (const float4*)proj, (const float4*)ef2, V_idx, E_idx, scores, nnz);
        pair_build<<<nChunks, 256, 0, stream>>>(E_idx, scores, vlist, cursor, nnz, nb);
    }

    int n4 = nnz / 4;
    hist1_kernel<<<128, 256, 0, stream>>>((const float4*)scores, hist1, n4, nnz);
    scan1_kernel<<<1, 256, 0, stream>>>(hist1, sel, kptr);
    compact_kernel<<<1024, 256, 0, stream>>>(
        (const float4*)scores, sel, cand, candCount, n4, nnz);
    select_small<<<1, 256, 0, stream>>>(cand, candCount, sel, tieList);

    edge_final<<<nb, 256, 0, stream>>>(vlist, bucketBase, sel, tieList,
                                       eprob, esoft, ehard, nhe);
    write_hard<<<1024, 256, 0, stream>>>(
        (const float4*)scores, sel, tieList, (float4*)hard, (float4*)soft, n4, nnz);
}

// Round 10
// 443.855 us; speedup vs baseline: 1.2853x; 1.0647x over previous
//
#include <hip/hip_runtime.h>
#include <math.h>

#define FEAT 256
#define RANKK 16
#define CAND_CAP 131072
#define TIE_CAP 2048
#define NBK_MAX 512   // max buckets (nhe/256)
#define PB_CHUNK 8192
#define SPLIT 4       // blocks per bucket in bucket_score
#define PRJ_NODES 64  // nodes per proj block (2n x 2r register tiling)
#define EH_BLOCKS 128
#define NW_BLOCKS 1024

typedef unsigned long long u64;

static __device__ __forceinline__ u64 pack_pair(unsigned e_low, unsigned bits, unsigned idx) {
    // [63:56]=e&255, [55:26]=score bits (<2^30 since score<=1.0f), [25:0]=idx
    return ((u64)e_low << 56) | ((u64)bits << 26) | (u64)idx;
}
// vlist entry: [63:40]=v (24b), [31:8]=idx (24b), [7:0]=e&255
static __device__ __forceinline__ u64 pack_v(unsigned v, unsigned idx, unsigned e_low) {
    return ((u64)v << 40) | ((u64)idx << 8) | (u64)e_low;
}

// ========== K1: prep_all = ehist(+scan) | gather_ef | proj, split by block range ==========
__global__ __launch_bounds__(256) void prep_all(
        const int* __restrict__ E_idx, unsigned* __restrict__ bucketCnt,
        unsigned* __restrict__ bucketBase, unsigned* __restrict__ cursor,
        unsigned* __restrict__ ticket, int nnz,
        const float4* __restrict__ ef, const int* __restrict__ edge_ids,
        float4* __restrict__ ef2, int nhe,
        const float* __restrict__ x, const float* __restrict__ Wm,
        float* __restrict__ proj, int n_nodes, int G) {
    __shared__ float smem[12608];   // overlaid: proj tiles / ehist hist+scan
    __shared__ unsigned isLast;
    int t = threadIdx.x;
    int bid = blockIdx.x;

    if (bid < EH_BLOCKS) {
        // ---- bucket histogram of E_idx>>8 + last-block exclusive scan ----
        unsigned* h  = (unsigned*)smem;            // 512
        unsigned* ps = ((unsigned*)smem) + 512;    // 256
        for (int j = t; j < NBK_MAX; j += 256) h[j] = 0;
        __syncthreads();
        for (int i = bid * 256 + t; i < nnz; i += EH_BLOCKS * 256)
            atomicAdd(&h[((unsigned)E_idx[i]) >> 8], 1u);
        __syncthreads();
        for (int j = t; j < NBK_MAX; j += 256)
            if (h[j]) atomicAdd(&bucketCnt[j], h[j]);
        __threadfence();
        if (t == 0) isLast = (atomicAdd(ticket, 1u) == EH_BLOCKS - 1) ? 1u : 0u;
        __syncthreads();
        if (!isLast) return;
        unsigned a0 = atomicAdd(&bucketCnt[2 * t], 0u);
        unsigned a1 = atomicAdd(&bucketCnt[2 * t + 1], 0u);
        unsigned pairsum = a0 + a1;
        ps[t] = pairsum;
        __syncthreads();
        for (int off = 1; off < 256; off <<= 1) {
            unsigned v = (t >= off) ? ps[t - off] : 0u;
            __syncthreads();
            ps[t] += v;
            __syncthreads();
        }
        unsigned excl = ps[t] - pairsum;
        bucketBase[2 * t] = excl;           cursor[2 * t] = excl;
        bucketBase[2 * t + 1] = excl + a0;  cursor[2 * t + 1] = excl + a0;
        if (t == 255) bucketBase[NBK_MAX] = ps[255];   // == nnz
        return;
    }
    if (bid < EH_BLOCKS + G) {
        // ---- gather_ef ----
        int tt = (bid - EH_BLOCKS) * 256 + t;
        if (tt < nhe * 4) {
            int e = tt >> 2, c = tt & 3;
            ef2[(size_t)e * 4 + c] = ef[(size_t)edge_ids[e] * 4 + c];
        }
        return;
    }
    // ---- proj: 2n x 2r register tiling, K-chunked (r9-proven) ----
    int pb = bid - EH_BLOCKS - G;
    float (*Ws)[FEAT + 4] = (float(*)[FEAT + 4])smem;            // 16x260
    float (*Xs)[128 + 4]  = (float(*)[128 + 4])(smem + 4160);    // 64x132
    const float4* x4 = (const float4*)x;
    const float4* w4 = (const float4*)Wm;
    for (int i = t; i < RANKK * 64; i += 256) {
        int r = i >> 6, c4 = i & 63;
        *(float4*)&Ws[r][c4 * 4] = w4[(size_t)r * 64 + c4];
    }
    int nodeBase = pb * PRJ_NODES;
    int np = t >> 3, rp = t & 7;
    int n0 = np * 2, r0 = rp * 2;
    double a00 = 0.0, a01 = 0.0, a10 = 0.0, a11 = 0.0;
    for (int chunk = 0; chunk < 2; ++chunk) {
        __syncthreads();
        for (int i = t; i < PRJ_NODES * 32; i += 256) {
            int row = i >> 5, c4 = i & 31;
            int node = nodeBase + row;
            float4 v = make_float4(0.f, 0.f, 0.f, 0.f);
            if (node < n_nodes) v = x4[(size_t)node * 64 + chunk * 32 + c4];
            *(float4*)&Xs[row][c4 * 4] = v;
        }
        __syncthreads();
        int jw = chunk * 128;
        #pragma unroll 8
        for (int j4 = 0; j4 < 32; ++j4) {
            float4 xa = *(const float4*)&Xs[n0][j4 * 4];
            float4 xb = *(const float4*)&Xs[n0 + 1][j4 * 4];
            float4 wa = *(const float4*)&Ws[r0][jw + j4 * 4];
            float4 wb = *(const float4*)&Ws[r0 + 1][jw + j4 * 4];
            a00 += (double)xa.x * wa.x + (double)xa.y * wa.y + (double)xa.z * wa.z + (double)xa.w * wa.w;
            a01 += (double)xa.x * wb.x + (double)xa.y * wb.y + (double)xa.z * wb.z + (double)xa.w * wb.w;
            a10 += (double)xb.x * wa.x + (double)xb.y * wa.y + (double)xb.z * wa.z + (double)xb.w * wa.w;
            a11 += (double)xb.x * wb.x + (double)xb.y * wb.y + (double)xb.z * wb.z + (double)xb.w * wb.w;
        }
    }
    int nodeA = nodeBase + n0;
    int nodeB = nodeA + 1;
    if (nodeA < n_nodes) {
        proj[(size_t)nodeA * RANKK + r0]     = (float)a00;
        proj[(size_t)nodeA * RANKK + r0 + 1] = (float)a01;
    }
    if (nodeB < n_nodes) {
        proj[(size_t)nodeB * RANKK + r0]     = (float)a10;
        proj[(size_t)nodeB * RANKK + r0 + 1] = (float)a11;
    }
}

// ========== K2: sort incidences into bucket order ==========
__global__ __launch_bounds__(256) void sort_kernel(const int* __restrict__ V_idx,
        const int* __restrict__ E_idx, u64* __restrict__ vlist,
        unsigned* __restrict__ cursor, int nnz, int nb) {
    __shared__ unsigned bh[NBK_MAX];
    int t = threadIdx.x;
    for (int j = t; j < NBK_MAX; j += 256) bh[j] = 0;
    __syncthreads();
    int base = blockIdx.x * PB_CHUNK;
    int nE = nnz - base;
    if (nE > PB_CHUNK) nE = PB_CHUNK;
    for (int o = t; o < nE; o += 256)
        atomicAdd(&bh[((unsigned)E_idx[base + o]) >> 8], 1u);
    __syncthreads();
    for (int b = t; b < nb; b += 256) {
        unsigned c = bh[b];
        bh[b] = c ? atomicAdd(&cursor[b], c) : 0u;
    }
    __syncthreads();
    for (int o = t; o < nE; o += 256) {
        int i = base + o;
        unsigned e = (unsigned)E_idx[i];
        unsigned v = (unsigned)V_idx[i];
        unsigned pos = atomicAdd(&bh[e >> 8], 1u);
        vlist[pos] = pack_v(v, (unsigned)i, e & 255u);
    }
}

// ========== K3 (primary): bucket-ordered score; ef2 tile in LDS; pairs in place ==========
__global__ __launch_bounds__(256) void bucket_score(
        const float4* __restrict__ proj4, const float4* __restrict__ ef4,
        const unsigned* __restrict__ bucketBase, u64* __restrict__ list,
        float* __restrict__ scores, int nhe) {
    __shared__ float efs[256][20];
    int t = threadIdx.x;
    int b = blockIdx.x >> 2;
    int part = blockIdx.x & (SPLIT - 1);
    for (int jj = t; jj < 1024; jj += 256) {
        int edge = (b << 8) + (jj >> 2);
        if (edge < nhe) {
            float4 v = ef4[(size_t)edge * 4 + (jj & 3)];
            *(float4*)&efs[jj >> 2][(jj & 3) * 4] = v;
        }
    }
    __syncthreads();
    unsigned n0 = bucketBase[b], n1 = bucketBase[b + 1];
    #pragma unroll 2
    for (unsigned j = n0 + (part << 8) + t; j < n1; j += SPLIT * 256) {
        u64 p = list[j];
        unsigned v   = (unsigned)(p >> 40);
        unsigned idx = (unsigned)(p >> 8) & 0xFFFFFFu;
        unsigned el  = (unsigned)(p & 255u);
        float4 p0 = proj4[(size_t)v * 4 + 0];
        float4 p1 = proj4[(size_t)v * 4 + 1];
        float4 p2 = proj4[(size_t)v * 4 + 2];
        float4 p3 = proj4[(size_t)v * 4 + 3];
        float4 f0 = *(const float4*)&efs[el][0];
        float4 f1 = *(const float4*)&efs[el][4];
        float4 f2 = *(const float4*)&efs[el][8];
        float4 f3 = *(const float4*)&efs[el][12];
        double acc = (double)p0.x * f0.x + (double)p0.y * f0.y + (double)p0.z * f0.z + (double)p0.w * f0.w
                   + (double)p1.x * f1.x + (double)p1.y * f1.y + (double)p1.z * f1.z + (double)p1.w * f1.w
                   + (double)p2.x * f2.x + (double)p2.y * f2.y + (double)p2.z * f2.z + (double)p2.w * f2.w
                   + (double)p3.x * f3.x + (double)p3.y * f3.y + (double)p3.z * f3.z + (double)p3.w * f3.w;
        float s = (float)(1.0 / (1.0 + exp(-acc)));
        scores[idx] = s;
        list[j] = pack_pair(el, __float_as_uint(s), idx);
    }
}

// ========== K3b/K3c (fallback when !wsBig): linear score + pair_build ==========
__global__ __launch_bounds__(256) void score_linear(
        const float4* __restrict__ proj4, const float4* __restrict__ ef4,
        const int* __restrict__ V_idx, const int* __restrict__ E_idx,
        float* __restrict__ scores, int nnz) {
    int stride = gridDim.x * blockDim.x;
    #pragma unroll 2
    for (int i = blockIdx.x * blockDim.x + threadIdx.x; i < nnz; i += stride) {
        int v = V_idx[i], e = E_idx[i];
        float4 p0 = proj4[(size_t)v * 4 + 0];
        float4 p1 = proj4[(size_t)v * 4 + 1];
        float4 p2 = proj4[(size_t)v * 4 + 2];
        float4 p3 = proj4[(size_t)v * 4 + 3];
        float4 f0 = ef4[(size_t)e * 4 + 0];
        float4 f1 = ef4[(size_t)e * 4 + 1];
        float4 f2 = ef4[(size_t)e * 4 + 2];
        float4 f3 = ef4[(size_t)e * 4 + 3];
        double acc = (double)p0.x * f0.x + (double)p0.y * f0.y + (double)p0.z * f0.z + (double)p0.w * f0.w
                   + (double)p1.x * f1.x + (double)p1.y * f1.y + (double)p1.z * f1.z + (double)p1.w * f1.w
                   + (double)p2.x * f2.x + (double)p2.y * f2.y + (double)p2.z * f2.z + (double)p2.w * f2.w
                   + (double)p3.x * f3.x + (double)p3.y * f3.y + (double)p3.z * f3.z + (double)p3.w * f3.w;
        scores[i] = (float)(1.0 / (1.0 + exp(-acc)));
    }
}
__global__ __launch_bounds__(256) void pair_build(const int* __restrict__ E_idx,
        const float* __restrict__ scores, u64* __restrict__ pairs,
        unsigned* __restrict__ cursor, int nnz, int nb) {
    __shared__ unsigned bh[NBK_MAX];
    for (int t = threadIdx.x; t < NBK_MAX; t += 256) bh[t] = 0;
    __syncthreads();
    int base = blockIdx.x * PB_CHUNK;
    int nE = nnz - base;
    if (nE > PB_CHUNK) nE = PB_CHUNK;
    for (int o = threadIdx.x; o < nE; o += 256)
        atomicAdd(&bh[((unsigned)E_idx[base + o]) >> 8], 1u);
    __syncthreads();
    for (int b = threadIdx.x; b < nb; b += 256) {
        unsigned c = bh[b];
        bh[b] = c ? atomicAdd(&cursor[b], c) : 0u;
    }
    __syncthreads();
    for (int o = threadIdx.x; o < nE; o += 256) {
        int i = base + o;
        unsigned e = (unsigned)E_idx[i];
        unsigned bits = __float_as_uint(scores[i]);
        unsigned pos = atomicAdd(&bh[e >> 8], 1u);
        pairs[pos] = pack_pair(e & 255u, bits, (unsigned)i);
    }
}

// ========== K4: hist1 + last-block scan1 (ticket, r6-proven pattern) ==========
__global__ __launch_bounds__(256) void hist1scan(const float4* __restrict__ scores4,
        unsigned* __restrict__ hist1g, unsigned* __restrict__ ticket,
        unsigned* __restrict__ sel, const int* __restrict__ kptr, int n4, int nnz) {
    __shared__ unsigned h[4096];
    __shared__ unsigned sfx[256];
    __shared__ unsigned isLast;
    int t = threadIdx.x;
    for (int j = t; j < 4096; j += 256) h[j] = 0;
    __syncthreads();
    unsigned r1016 = 0, r1015 = 0, r0 = 0;
    int stride = gridDim.x * 256;
    for (int i = blockIdx.x * 256 + t; i < n4; i += stride) {
        float4 sv = scores4[i];
        unsigned bb[4] = {__float_as_uint(sv.x), __float_as_uint(sv.y),
                          __float_as_uint(sv.z), __float_as_uint(sv.w)};
        #pragma unroll
        for (int q = 0; q < 4; ++q) {
            unsigned b = bb[q] >> 20;
            if (b == 1016) ++r1016;
            else if (b == 1015) ++r1015;
            else if (b == 0) ++r0;
            else atomicAdd(&h[b], 1u);
        }
    }
    for (int i = n4 * 4 + blockIdx.x * 256 + t; i < nnz; i += stride) {
        unsigned b = __float_as_uint(((const float*)scores4)[i]) >> 20;
        if (b == 1016) ++r1016;
        else if (b == 1015) ++r1015;
        else if (b == 0) ++r0;
        else atomicAdd(&h[b], 1u);
    }
    if (r1016) atomicAdd(&h[1016], r1016);
    if (r1015) atomicAdd(&h[1015], r1015);
    if (r0) atomicAdd(&h[0], r0);
    __syncthreads();
    for (int j = t; j < 4096; j += 256)
        if (h[j]) atomicAdd(&hist1g[j], h[j]);
    __threadfence();
    if (t == 0) isLast = (atomicAdd(ticket, 1u) == gridDim.x - 1) ? 1u : 0u;
    __syncthreads();
    if (!isLast) return;
    // ---- scan1 on final histogram (atomic reads for coherence) ----
    unsigned local[16];
    unsigned s = 0;
    #pragma unroll
    for (int j = 0; j < 16; ++j) { local[j] = atomicAdd(&hist1g[t * 16 + j], 0u); s += local[j]; }
    sfx[t] = s;
    __syncthreads();
    for (int off = 1; off < 256; off <<= 1) {
        unsigned add = (t + off < 256) ? sfx[t + off] : 0;
        __syncthreads();
        sfx[t] += add;
        __syncthreads();
    }
    unsigned krem = (unsigned)(*kptr);
    unsigned above = (t + 1 < 256) ? sfx[t + 1] : 0;
    if (above < krem && sfx[t] >= krem) {
        unsigned cum = above;
        int b = t * 16;
        for (int j = 15; j >= 0; --j) {
            unsigned cc = local[j];
            if (cum + cc >= krem) { b = t * 16 + j; break; }
            cum += cc;
        }
        sel[0] = krem - cum;
        sel[1] = ((unsigned)b) << 20;
    }
}

// ========== K5: compact candidates ==========
__global__ void compact_kernel(const float4* __restrict__ scores4,
                               const unsigned* __restrict__ sel,
                               uint2* __restrict__ cand, unsigned* __restrict__ candCount,
                               int n4, int nnz) {
    unsigned pref = sel[1] >> 20;
    int tid = blockIdx.x * blockDim.x + threadIdx.x;
    int stride = gridDim.x * blockDim.x;
    int lane = threadIdx.x & 63;
    int niter = (n4 + stride - 1) / stride;
    for (int kk = 0; kk < niter; ++kk) {
        int i = tid + kk * stride;
        bool inb = (i < n4);
        float4 sv = make_float4(0.f, 0.f, 0.f, 0.f);
        if (inb) sv = scores4[i];
        unsigned bb[4] = {__float_as_uint(sv.x), __float_as_uint(sv.y),
                          __float_as_uint(sv.z), __float_as_uint(sv.w)};
        #pragma unroll
        for (int q = 0; q < 4; ++q) {
            bool pred = inb && ((bb[q] >> 20) == pref);
            unsigned long long mask = __ballot(pred);
            if (mask) {
                int leader = __ffsll(mask) - 1;
                unsigned base = 0;
                if (lane == leader) base = atomicAdd(candCount, (unsigned)__popcll(mask));
                base = __shfl(base, leader, 64);
                if (pred) {
                    unsigned rank = __popcll(mask & ((1ull << lane) - 1ull));
                    unsigned pos = base + rank;
                    if (pos < CAND_CAP) cand[pos] = make_uint2(bb[q], (unsigned)(i * 4 + q));
                }
            }
        }
    }
    for (int i = n4 * 4 + tid; i < nnz; i += stride) {
        unsigned b = __float_as_uint(((const float*)scores4)[i]);
        if ((b >> 20) == pref) {
            unsigned pos = atomicAdd(candCount, 1u);
            if (pos < CAND_CAP) cand[pos] = make_uint2(b, (unsigned)i);
        }
    }
}

// ========== K6: single-block selection among candidates ==========
__global__ __launch_bounds__(256) void select_small(const uint2* __restrict__ cand,
                            const unsigned* __restrict__ candCount,
                            unsigned* __restrict__ sel, unsigned* __restrict__ tieList) {
    __shared__ unsigned h2[4096];
    __shared__ unsigned sfx[256];
    __shared__ unsigned sB2, sKrem2, sT, sM;
    __shared__ unsigned h3[256];
    __shared__ unsigned ties[TIE_CAP];
    __shared__ unsigned tcnt;
    int t = threadIdx.x;
    unsigned nc = *candCount;
    int n = (nc < CAND_CAP) ? (int)nc : CAND_CAP;
    unsigned krem = sel[0];
    unsigned pref = sel[1];

    for (int j = t; j < 4096; j += 256) h2[j] = 0;
    if (t == 0) tcnt = 0;
    __syncthreads();
    for (int j = t; j < n; j += 256) atomicAdd(&h2[(cand[j].x >> 8) & 0xFFF], 1u);
    __syncthreads();

    unsigned local[16];
    unsigned s = 0;
    #pragma unroll
    for (int j = 0; j < 16; ++j) { local[j] = h2[t * 16 + j]; s += local[j]; }
    sfx[t] = s;
    __syncthreads();
    for (int off = 1; off < 256; off <<= 1) {
        unsigned add = (t + off < 256) ? sfx[t + off] : 0;
        __syncthreads();
        sfx[t] += add;
        __syncthreads();
    }
    {
        unsigned above = (t + 1 < 256) ? sfx[t + 1] : 0;
        if (above < krem && sfx[t] >= krem) {
            unsigned cum = above;
            int b = t * 16;
            for (int j = 15; j >= 0; --j) {
                unsigned cc = local[j];
                if (cum + cc >= krem) { b = t * 16 + j; break; }
                cum += cc;
            }
            sB2 = (unsigned)b;
            sKrem2 = krem - cum;
        }
    }
    __syncthreads();

    h3[t] = 0;
    __syncthreads();
    unsigned b2 = sB2;
    for (int j = t; j < n; j += 256) {
        unsigned x = cand[j].x;
        if (((x >> 8) & 0xFFF) == b2) atomicAdd(&h3[x & 0xFF], 1u);
    }
    __syncthreads();
    sfx[t] = h3[t];
    __syncthreads();
    for (int off = 1; off < 256; off <<= 1) {
        unsigned add = (t + off < 256) ? sfx[t + off] : 0;
        __syncthreads();
        sfx[t] += add;
        __syncthreads();
    }
    {
        unsigned krem2 = sKrem2;
        unsigned above = (t + 1 < 256) ? sfx[t + 1] : 0;
        if (above < krem2 && sfx[t] >= krem2) {
            sT = pref | (b2 << 8) | (unsigned)t;
            sM = krem2 - above;
        }
    }
    __syncthreads();

    unsigned T = sT;
    for (int j = t; j < n; j += 256) {
        if (cand[j].x == T) {
            unsigned p = atomicAdd(&tcnt, 1u);
            if (p < TIE_CAP) ties[p] = cand[j].y;
        }
    }
    __syncthreads();
    if (t == 0) {
        unsigned cnt = (tcnt < TIE_CAP) ? tcnt : TIE_CAP;
        for (unsigned a = 1; a < cnt; ++a) {
            unsigned key = ties[a];
            int bpos = (int)a - 1;
            while (bpos >= 0 && ties[bpos] > key) { ties[bpos + 1] = ties[bpos]; --bpos; }
            ties[bpos + 1] = key;
        }
        unsigned m = sM;
        if (m > cnt) m = cnt;
        sel[2] = T;
        sel[3] = m;
        for (unsigned j = 0; j < m; ++j) tieList[j] = ties[j];
    }
}

// ========== K7 (wsHuge): fused edge_final + write_hard — pairs in d_ws, no aliasing ==========
__global__ __launch_bounds__(256) void final_combo(const u64* __restrict__ pairs,
        const unsigned* __restrict__ bucketBase, const unsigned* __restrict__ sel,
        const unsigned* __restrict__ tieList, const float4* __restrict__ scores4,
        float* __restrict__ eprob, float* __restrict__ esoft, float* __restrict__ ehard,
        float4* __restrict__ hard4, float4* __restrict__ soft4,
        int nb, int n4, int nnz, int nhe) {
    __shared__ float ss[256];
    __shared__ unsigned cc[256];
    __shared__ unsigned hh[256];
    __shared__ unsigned ties[TIE_CAP];
    unsigned T = sel[2];
    unsigned m = sel[3];
    if (m > TIE_CAP) m = TIE_CAP;
    int t = threadIdx.x;
    for (int j = t; j < (int)m; j += 256) ties[j] = tieList[j];

    if ((int)blockIdx.x < nb) {
        ss[t] = 0.f; cc[t] = 0u; hh[t] = 0u;
        __syncthreads();
        int b = blockIdx.x;
        unsigned n0 = bucketBase[b], n1 = bucketBase[b + 1];
        for (unsigned j = n0 + t; j < n1; j += 256) {
            u64 p = pairs[j];
            unsigned el = (unsigned)(p >> 56);
            unsigned bits = (unsigned)(p >> 26) & 0x3FFFFFFFu;
            atomicAdd(&ss[el], __uint_as_float(bits));
            atomicAdd(&cc[el], 1u);
            bool keep = bits > T;
            if (bits == T) {
                unsigned idx = (unsigned)(p & 0x3FFFFFFu);
                int lo = 0, hi = (int)m - 1;
                keep = false;
                while (lo <= hi) {
                    int mid = (lo + hi) >> 1;
                    unsigned v = ties[mid];
                    if (v == idx) { keep = true; break; }
                    if (v < idx) lo = mid + 1; else hi = mid - 1;
                }
            }
            if (keep) atomicAdd(&hh[el], 1u);
        }
        __syncthreads();
        int e = blockIdx.x * 256 + t;
        if (e < nhe) {
            float c = fmaxf((float)cc[t], 1.0f);
            eprob[e] = ss[t] / c;
            esoft[e] = (float)hh[t] / c;
            ehard[e] = (hh[t] > 0) ? 1.0f : 0.0f;
        }
        return;
    }
    __syncthreads();
    int tid = (blockIdx.x - nb) * 256 + t;
    int stride = NW_BLOCKS * 256;
    for (int i = tid; i < n4; i += stride) {
        float4 sv = scores4[i];
        unsigned bb[4] = {__float_as_uint(sv.x), __float_as_uint(sv.y),
                          __float_as_uint(sv.z), __float_as_uint(sv.w)};
        float hv[4];
        #pragma unroll
        for (int q = 0; q < 4; ++q) {
            bool keep = (bb[q] > T);
            if (bb[q] == T) {
                unsigned idx = (unsigned)(i * 4 + q);
                int lo = 0, hi = (int)m - 1;
                keep = false;
                while (lo <= hi) {
                    int mid = (lo + hi) >> 1;
                    unsigned v = ties[mid];
                    if (v == idx) { keep = true; break; }
                    if (v < idx) lo = mid + 1; else hi = mid - 1;
                }
            }
            hv[q] = keep ? 1.0f : 0.0f;
        }
        float4 outv = make_float4(hv[0], hv[1], hv[2], hv[3]);
        hard4[i] = outv;
        soft4[i] = outv;
    }
    const float* sc = (const float*)scores4;
    float* hard = (float*)hard4;
    float* soft = (float*)soft4;
    for (int i = n4 * 4 + tid; i < nnz; i += stride) {
        unsigned b = __float_as_uint(sc[i]);
        bool keep = (b > T);
        if (b == T) {
            unsigned idx = (unsigned)i;
            int lo = 0, hi = (int)m - 1;
            keep = false;
            while (lo <= hi) {
                int mid = (lo + hi) >> 1;
                unsigned v = ties[mid];
                if (v == idx) { keep = true; break; }
                if (v < idx) lo = mid + 1; else hi = mid - 1;
            }
        }
        float hvv = keep ? 1.0f : 0.0f;
        hard[i] = hvv;
        soft[i] = hvv;
    }
}

// ========== K7b/K7c (fallback when pairs aliases soft/hard): sequential versions ==========
__global__ __launch_bounds__(256) void edge_final(const u64* __restrict__ pairs,
        const unsigned* __restrict__ bucketBase, const unsigned* __restrict__ sel,
        const unsigned* __restrict__ tieList,
        float* __restrict__ eprob, float* __restrict__ esoft, float* __restrict__ ehard,
        int nhe) {
    __shared__ float ss[256];
    __shared__ unsigned cc[256];
    __shared__ unsigned hh[256];
    __shared__ unsigned ties[TIE_CAP];
    unsigned T = sel[2];
    unsigned m = sel[3];
    if (m > TIE_CAP) m = TIE_CAP;
    int t = threadIdx.x;
    ss[t] = 0.f; cc[t] = 0u; hh[t] = 0u;
    for (int j = t; j < (int)m; j += 256) ties[j] = tieList[j];
    __syncthreads();
    int b = blockIdx.x;
    unsigned n0 = bucketBase[b], n1 = bucketBase[b + 1];
    for (unsigned j = n0 + t; j < n1; j += 256) {
        u64 p = pairs[j];
        unsigned el = (unsigned)(p >> 56);
        unsigned bits = (unsigned)(p >> 26) & 0x3FFFFFFFu;
        atomicAdd(&ss[el], __uint_as_float(bits));
        atomicAdd(&cc[el], 1u);
        bool keep = bits > T;
        if (bits == T) {
            unsigned idx = (unsigned)(p & 0x3FFFFFFu);
            int lo = 0, hi = (int)m - 1;
            keep = false;
            while (lo <= hi) {
                int mid = (lo + hi) >> 1;
                unsigned v = ties[mid];
                if (v == idx) { keep = true; break; }
                if (v < idx) lo = mid + 1; else hi = mid - 1;
            }
        }
        if (keep) atomicAdd(&hh[el], 1u);
    }
    __syncthreads();
    int e = b * 256 + t;
    if (e < nhe) {
        float c = fmaxf((float)cc[t], 1.0f);
        eprob[e] = ss[t] / c;
        esoft[e] = (float)hh[t] / c;
        ehard[e] = (hh[t] > 0) ? 1.0f : 0.0f;
    }
}
__global__ __launch_bounds__(256) void write_hard(const float4* __restrict__ scores4,
                           const unsigned* __restrict__ sel,
                           const unsigned* __restrict__ tieList,
                           float4* __restrict__ hard4, float4* __restrict__ soft4,
                           int n4, int nnz) {
    __shared__ unsigned ties[TIE_CAP];
    unsigned T = sel[2];
    unsigned m = sel[3];
    if (m > TIE_CAP) m = TIE_CAP;
    for (int j = threadIdx.x; j < (int)m; j += blockDim.x) ties[j] = tieList[j];
    __syncthreads();
    int tid = blockIdx.x * blockDim.x + threadIdx.x;
    int stride = gridDim.x * blockDim.x;
    for (int i = tid; i < n4; i += stride) {
        float4 sv = scores4[i];
        unsigned bb[4] = {__float_as_uint(sv.x), __float_as_uint(sv.y),
                          __float_as_uint(sv.z), __float_as_uint(sv.w)};
        float hv[4];
        #pragma unroll
        for (int q = 0; q < 4; ++q) {
            bool keep = (bb[q] > T);
            if (bb[q] == T) {
                unsigned idx = (unsigned)(i * 4 + q);
                int lo = 0, hi = (int)m - 1;
                keep = false;
                while (lo <= hi) {
                    int mid = (lo + hi) >> 1;
                    unsigned v = ties[mid];
                    if (v == idx) { keep = true; break; }
                    if (v < idx) lo = mid + 1; else hi = mid - 1;
                }
            }
            hv[q] = keep ? 1.0f : 0.0f;
        }
        float4 outv = make_float4(hv[0], hv[1], hv[2], hv[3]);
        hard4[i] = outv;
        soft4[i] = outv;
    }
    const float* sc = (const float*)scores4;
    float* hard = (float*)hard4;
    float* soft = (float*)soft4;
    for (int i = n4 * 4 + tid; i < nnz; i += stride) {
        unsigned b = __float_as_uint(sc[i]);
        bool keep = (b > T);
        if (b == T) {
            unsigned idx = (unsigned)i;
            int lo = 0, hi = (int)m - 1;
            keep = false;
            while (lo <= hi) {
                int mid = (lo + hi) >> 1;
                unsigned v = ties[mid];
                if (v == idx) { keep = true; break; }
                if (v < idx) lo = mid + 1; else hi = mid - 1;
            }
        }
        float hvv = keep ? 1.0f : 0.0f;
        hard[i] = hvv;
        soft[i] = hvv;
    }
}

extern "C" void kernel_launch(void* const* d_in, const int* in_sizes, int n_in,
                              void* d_out, int out_size, void* d_ws, size_t ws_size,
                              hipStream_t stream) {
    const float* x        = (const float*)d_in[0];
    const float* Wm       = (const float*)d_in[1];
    const float* ef       = (const float*)d_in[2];
    const int*   V_idx    = (const int*)d_in[3];
    const int*   E_idx    = (const int*)d_in[4];
    const int*   edge_ids = (const int*)d_in[5];
    const int*   kptr     = (const int*)d_in[6];

    const int nnz     = in_sizes[3];
    const int nhe     = in_sizes[5];
    const int n_nodes = in_sizes[0] / FEAT;
    const int nb      = (nhe + 255) >> 8;

    float* out    = (float*)d_out;
    float* scores = out;
    float* soft   = out + (size_t)nnz;
    float* hard   = out + 2 * (size_t)nnz;
    float* eprob  = out + 3 * (size_t)nnz;
    float* esoft  = eprob + nhe;
    float* ehard  = esoft + nhe;

    uint2* cand = (uint2*)eprob;   // consumed by select before eprob is written

    // ---- aux zone in d_ws ----
    char* w = (char*)d_ws;
    unsigned* hist1      = (unsigned*)w;               // 4096 (zeroed)
    unsigned* bucketCnt  = hist1 + 4096;               // NBK_MAX (zeroed)
    unsigned* candCount  = bucketCnt + NBK_MAX;        // 1 (zeroed)
    unsigned* ticket1    = candCount + 1;              // 1 (zeroed)
    unsigned* ticket2    = ticket1 + 1;                // 1 (zeroed)
    unsigned* sel        = ticket2 + 1;                // 8
    unsigned* tieList    = sel + 8;                    // TIE_CAP
    unsigned* bucketBase = tieList + TIE_CAP;          // NBK_MAX+1
    unsigned* cursor     = bucketBase + NBK_MAX + 1;   // NBK_MAX
    char* auxEnd = (char*)(cursor + NBK_MAX);
    size_t auxAligned = (((size_t)(auxEnd - w)) + 255) & ~(size_t)255;
    size_t zeroBytes = (size_t)(4096 + NBK_MAX + 3) * sizeof(unsigned);

    size_t ef2Bytes   = (size_t)nhe * RANKK * sizeof(float);
    size_t projBytes  = (size_t)n_nodes * RANKK * sizeof(float);
    size_t pairsBytes = (size_t)nnz * sizeof(u64);

    bool wsBig  = (ws_size >= auxAligned + ef2Bytes + projBytes);
    bool wsHuge = (ws_size >= auxAligned + ef2Bytes + projBytes + pairsBytes);

    float* ef2;
    float* proj;
    u64*   vlist;
    if (wsBig) {
        ef2  = (float*)(w + auxAligned);
        proj = (float*)(w + auxAligned + ef2Bytes);
        vlist = wsHuge ? (u64*)(w + auxAligned + ef2Bytes + projBytes) : (u64*)soft;
    } else {
        ef2  = hard;   // consumed by score before pairs scatter touches hard
        proj = hard + (size_t)nhe * RANKK;
        vlist = (u64*)soft;
    }

    hipMemsetAsync(w, 0, zeroBytes, stream);

    int G = (nhe * 4 + 255) / 256;
    int P = (n_nodes + PRJ_NODES - 1) / PRJ_NODES;
    prep_all<<<EH_BLOCKS + G + P, 256, 0, stream>>>(
        E_idx, bucketCnt, bucketBase, cursor, ticket1, nnz,
        (const float4*)ef, edge_ids, (float4*)ef2, nhe,
        x, Wm, proj, n_nodes, G);

    int nChunks = (nnz + PB_CHUNK - 1) / PB_CHUNK;
    if (wsBig) {
        sort_kernel<<<nChunks, 256, 0, stream>>>(V_idx, E_idx, vlist, cursor, nnz, nb);
        bucket_score<<<nb * SPLIT, 256, 0, stream>>>(
            (const float4*)proj, (const float4*)ef2, bucketBase, vlist, scores, nhe);
    } else {
        score_linear<<<2048, 256, 0, stream>>>(
            (const float4*)proj, (const float4*)ef2, V_idx, E_idx, scores, nnz);
        pair_build<<<nChunks, 256, 0, stream>>>(E_idx, scores, vlist, cursor, nnz, nb);
    }

    int n4 = nnz / 4;
    hist1scan<<<128, 256, 0, stream>>>((const float4*)scores, hist1, ticket2,
                                       sel, kptr, n4, nnz);
    compact_kernel<<<1024, 256, 0, stream>>>(
        (const float4*)scores, sel, cand, candCount, n4, nnz);
    select_small<<<1, 256, 0, stream>>>(cand, candCount, sel, tieList);

    if (wsHuge) {
        // pairs live in d_ws — no aliasing with soft/hard: safe to fuse
        final_combo<<<nb + NW_BLOCKS, 256, 0, stream>>>(
            vlist, bucketBase, sel, tieList, (const float4*)scores,
            eprob, esoft, ehard, (float4*)hard, (float4*)soft, nb, n4, nnz, nhe);
    } else {
        // pairs alias soft/hard: edge_final must fully precede write_hard
        edge_final<<<nb, 256, 0, stream>>>(vlist, bucketBase, sel, tieList,
                                           eprob, esoft, ehard, nhe);
        write_hard<<<1024, 256, 0, stream>>>(
            (const float4*)scores, sel, tieList, (float4*)hard, (float4*)soft, n4, nnz);
    }
}